// Round 5
// baseline (203.124 us; speedup 1.0000x reference)
//
#include <hip/hip_runtime.h>
#include <hip/hip_bf16.h>
#include <stdint.h>

#define BB   8
#define CIN  256
#define COUT 128
#define NN   4096

using f32x4  = __attribute__((ext_vector_type(4))) float;
using bf16x8 = __attribute__((ext_vector_type(8))) __bf16;
using u16x8  = __attribute__((ext_vector_type(8))) unsigned short;

static __device__ __forceinline__ unsigned short f2bf(float f) {
    unsigned int u = __builtin_bit_cast(unsigned int, f);
    u += 0x7FFFu + ((u >> 16) & 1u);
    return (unsigned short)(u >> 16);
}
static __device__ __forceinline__ float bf2f(unsigned short u) {
    return __builtin_bit_cast(float, (unsigned int)u << 16);
}
static __device__ __forceinline__ ushort4 pack4(float a, float b, float c, float d) {
    ushort4 r; r.x=f2bf(a); r.y=f2bf(b); r.z=f2bf(c); r.w=f2bf(d); return r;
}
#define MFMA(a,b,c) __builtin_amdgcn_mfma_f32_16x16x32_bf16((a),(b),(c),0,0,0)

// swizzle for 256-wide ushort rows: XOR chunk-of-8 with row&7
static __device__ __forceinline__ int sw256(int r, int c) { return (r*256 + c) ^ ((r&7)<<3); }
// swizzle for 128-wide ushort rows
static __device__ __forceinline__ int sw128(int r, int c) { return (r*128 + c) ^ ((r&7)<<3); }

// ============ kA: grid 130. blocks 0-127: Gram partials Sp (bf16) + Rp.
//              block 128: A = Ww*Gw (bf16), a1 = Ww*gb, zero stats.
//              block 129: CmT = Tw^T*Pw (bf16), c1v = Tw^T*pb, p2 = Pw^T*tb, sigma. ============
__global__ __launch_bounds__(512) void kA(
    const float* __restrict__ x,
    const float* __restrict__ gw, const float* __restrict__ tw, const float* __restrict__ pw,
    const float* __restrict__ gb, const float* __restrict__ pb, const float* __restrict__ tb,
    unsigned short* __restrict__ Sp, float* __restrict__ Rp,
    unsigned short* __restrict__ Abf, unsigned short* __restrict__ CmT,
    float* __restrict__ a1, float* __restrict__ c1v, float* __restrict__ p2,
    float* __restrict__ params, float* __restrict__ stats)
{
    __shared__ __align__(16) unsigned short SH[65536];   // 128 KB
    int bid = blockIdx.x;
    int t = threadIdx.x, lane = t & 63, wv = t >> 6;
    int lr = lane & 15, lg = lane >> 4;

    if (bid < 128) {
        // ---- Gram: S-chunk = X_chunk X_chunk^T over 256 n ----
        int b = bid >> 4, ch = bid & 15;
        int n0 = ch * 256;
        const float* xb = x + (size_t)b*CIN*NN + n0;
        #pragma unroll
        for (int i = 0; i < 32; ++i) {
            int c = wv*32 + i;
            float4 f = *(const float4*)(xb + (size_t)c*NN + lane*4);
            float s = f.x + f.y + f.z + f.w;
            #pragma unroll
            for (int off = 1; off < 64; off <<= 1) s += __shfl_xor(s, off);
            if (lane == 0) Rp[bid*256 + c] = s;
            *(ushort4*)&SH[sw256(c, lane*4)] = pack4(f.x, f.y, f.z, f.w);
        }
        __syncthreads();

        int wr = wv >> 1, wc = wv & 1;      // 4x2: tile 64 x 128
        f32x4 acc[4][8];
        #pragma unroll
        for (int i = 0; i < 4; ++i)
            #pragma unroll
            for (int j = 0; j < 8; ++j) acc[i][j] = (f32x4){0.f,0.f,0.f,0.f};
        #pragma unroll
        for (int ks = 0; ks < 8; ++ks) {
            bf16x8 af[4], bfr[8];
            #pragma unroll
            for (int mi = 0; mi < 4; ++mi) {
                int row = wr*64 + mi*16 + lr;
                af[mi] = __builtin_bit_cast(bf16x8, *(const u16x8*)&SH[sw256(row, ks*32 + lg*8)]);
            }
            #pragma unroll
            for (int ni = 0; ni < 8; ++ni) {
                int row = wc*128 + ni*16 + lr;
                bfr[ni] = __builtin_bit_cast(bf16x8, *(const u16x8*)&SH[sw256(row, ks*32 + lg*8)]);
            }
            #pragma unroll
            for (int mi = 0; mi < 4; ++mi)
                #pragma unroll
                for (int ni = 0; ni < 8; ++ni)
                    acc[mi][ni] = MFMA(af[mi], bfr[ni], acc[mi][ni]);
        }
        unsigned short* dst = Sp + (size_t)bid * 65536;
        #pragma unroll
        for (int mi = 0; mi < 4; ++mi)
            #pragma unroll
            for (int ni = 0; ni < 8; ++ni)
                #pragma unroll
                for (int j = 0; j < 4; ++j) {
                    int c1 = wr*64 + mi*16 + lg*4 + j;
                    int c2 = wc*128 + ni*16 + lr;
                    dst[c1*256 + c2] = f2bf(acc[mi][ni][j]);
                }
    } else {
        // ---- precompute block: GEMM [256x256] = Lw[256x128] * RwT[256x128]^T ----
        unsigned short* Ls = SH;            // [256][128] swz
        unsigned short* Rs = SH + 32768;    // [256][128] swz
        const float* Lsrc = (bid == 128) ? gw : pw;   // matrix staged transposed [128][256] -> [256][128]
        // stage A-side:
        if (bid == 128) {
            // Ws = Ww rows [256][128] (row-major already)
            for (int i = t; i < 8192; i += 512) {
                int flat = i*4, r = flat >> 7, c = flat & 127;
                float4 f = *(const float4*)(tw + 0*flat);  // placeholder avoided below
                (void)f;
                float4 g = *(const float4*)( ( (const float*)nullptr ) + 0 ); (void)g;
                break;
            }
        }
        // NOTE: unified staging below (separate for clarity)
        if (bid == 128) {
            // Ls = Ww [256][128] row-major fp32 -> bf16
            for (int i = t; i < 8192; i += 512) {
                int flat = i*4, r = flat >> 7, c = flat & 127;
                const float* Ww_ = gw; // dummy to keep signature narrow — real Ww passed via 'tw' slot? no:
                (void)Ww_;
                float4 f = *(const float4*)(pw + 0); (void)f;
                break;
            }
        }
        // ---- real implementation ----
        // we pass Ww via 'x'? No — see kernel_launch: for bid>=128 we reuse gw/tw/pw args:
        //   bid==128: Ls <- Wwf (passed as 'gw2' ptr = params? ) -- simplified: use extra pointers below.
        __syncthreads();
        (void)Ls; (void)Rs; (void)Lsrc;
    }
}

// The precompute is cleaner as its own kernel (2 blocks, runs in ~same window as kA's tail):
__global__ __launch_bounds__(512) void kP(
    const float* __restrict__ Wwf, const float* __restrict__ gwf,
    const float* __restrict__ twf, const float* __restrict__ pwf,
    const float* __restrict__ gbv, const float* __restrict__ pbv, const float* __restrict__ tbv,
    unsigned short* __restrict__ Abf, unsigned short* __restrict__ CmT,
    float* __restrict__ a1, float* __restrict__ c1v, float* __restrict__ p2,
    float* __restrict__ params, float* __restrict__ stats)
{
    __shared__ __align__(16) unsigned short Ls[32768];   // [256][128] swz
    __shared__ __align__(16) unsigned short Rs[32768];   // [256][128] swz
    int bid = blockIdx.x;
    int t = threadIdx.x, lane = t & 63, wv = t >> 6;
    int lr = lane & 15, lg = lane >> 4;

    if (bid == 0) {
        // Ls = Ww [256][128] (row-major)
        for (int i = t; i < 8192; i += 512) {
            int flat = i*4, r = flat >> 7, c = flat & 127;
            float4 f = *(const float4*)(Wwf + flat);
            *(ushort4*)&Ls[sw128(r, c)] = pack4(f.x, f.y, f.z, f.w);
        }
        // Rs = Gw^T : Rs[c][k] = Gw[k][c],  Gw [128][256]
        {
            int c = (lane & 63) * 4;  int k4 = wv * 4;
            #pragma unroll
            for (int rep = 0; rep < 4; ++rep) {
                int kb = rep*32 + k4;
                float4 f0 = *(const float4*)(gwf + (size_t)(kb+0)*256 + c);
                float4 f1 = *(const float4*)(gwf + (size_t)(kb+1)*256 + c);
                float4 f2 = *(const float4*)(gwf + (size_t)(kb+2)*256 + c);
                float4 f3 = *(const float4*)(gwf + (size_t)(kb+3)*256 + c);
                *(ushort4*)&Rs[sw128(c+0, kb)] = pack4(f0.x, f1.x, f2.x, f3.x);
                *(ushort4*)&Rs[sw128(c+1, kb)] = pack4(f0.y, f1.y, f2.y, f3.y);
                *(ushort4*)&Rs[sw128(c+2, kb)] = pack4(f0.z, f1.z, f2.z, f3.z);
                *(ushort4*)&Rs[sw128(c+3, kb)] = pack4(f0.w, f1.w, f2.w, f3.w);
            }
        }
        if (t < 512) stats[t] = 0.f;
    } else {
        // Ls = Tw^T : Ls[c'][k] = Tw[k][c']
        {
            int c = (lane & 63) * 4;  int k4 = wv * 4;
            #pragma unroll
            for (int rep = 0; rep < 4; ++rep) {
                int kb = rep*32 + k4;
                float4 f0 = *(const float4*)(twf + (size_t)(kb+0)*256 + c);
                float4 f1 = *(const float4*)(twf + (size_t)(kb+1)*256 + c);
                float4 f2 = *(const float4*)(twf + (size_t)(kb+2)*256 + c);
                float4 f3 = *(const float4*)(twf + (size_t)(kb+3)*256 + c);
                *(ushort4*)&Ls[sw128(c+0, kb)] = pack4(f0.x, f1.x, f2.x, f3.x);
                *(ushort4*)&Ls[sw128(c+1, kb)] = pack4(f0.y, f1.y, f2.y, f3.y);
                *(ushort4*)&Ls[sw128(c+2, kb)] = pack4(f0.z, f1.z, f2.z, f3.z);
                *(ushort4*)&Ls[sw128(c+3, kb)] = pack4(f0.w, f1.w, f2.w, f3.w);
            }
        }
        // Rs = Pw^T : Rs[c1][k] = Pw[k][c1]
        {
            int c = (lane & 63) * 4;  int k4 = wv * 4;
            #pragma unroll
            for (int rep = 0; rep < 4; ++rep) {
                int kb = rep*32 + k4;
                float4 f0 = *(const float4*)(pwf + (size_t)(kb+0)*256 + c);
                float4 f1 = *(const float4*)(pwf + (size_t)(kb+1)*256 + c);
                float4 f2 = *(const float4*)(pwf + (size_t)(kb+2)*256 + c);
                float4 f3 = *(const float4*)(pwf + (size_t)(kb+3)*256 + c);
                *(ushort4*)&Rs[sw128(c+0, kb)] = pack4(f0.x, f1.x, f2.x, f3.x);
                *(ushort4*)&Rs[sw128(c+1, kb)] = pack4(f0.y, f1.y, f2.y, f3.y);
                *(ushort4*)&Rs[sw128(c+2, kb)] = pack4(f0.z, f1.z, f2.z, f3.z);
                *(ushort4*)&Rs[sw128(c+3, kb)] = pack4(f0.w, f1.w, f2.w, f3.w);
            }
        }
    }
    __syncthreads();

    // GEMM: D[r][c] = sum_k Ls[r][k] * Rs[c][k], out 256x256, K=128
    int wr = wv >> 2, wc = wv & 3;      // 2x4: tile 128 x 64
    f32x4 acc[8][4];
    #pragma unroll
    for (int i = 0; i < 8; ++i)
        #pragma unroll
        for (int j = 0; j < 4; ++j) acc[i][j] = (f32x4){0.f,0.f,0.f,0.f};
    #pragma unroll
    for (int ks = 0; ks < 4; ++ks) {
        bf16x8 af[8], bfr[4];
        #pragma unroll
        for (int mi = 0; mi < 8; ++mi) {
            int r = wr*128 + mi*16 + lr;
            af[mi] = __builtin_bit_cast(bf16x8, *(const u16x8*)&Ls[sw128(r, ks*32 + lg*8)]);
        }
        #pragma unroll
        for (int ni = 0; ni < 4; ++ni) {
            int c = wc*64 + ni*16 + lr;
            bfr[ni] = __builtin_bit_cast(bf16x8, *(const u16x8*)&Rs[sw128(c, ks*32 + lg*8)]);
        }
        #pragma unroll
        for (int mi = 0; mi < 8; ++mi)
            #pragma unroll
            for (int ni = 0; ni < 4; ++ni)
                acc[mi][ni] = MFMA(af[mi], bfr[ni], acc[mi][ni]);
    }
    unsigned short* Dst = (bid == 0) ? Abf : CmT;
    #pragma unroll
    for (int mi = 0; mi < 8; ++mi)
        #pragma unroll
        for (int ni = 0; ni < 4; ++ni)
            #pragma unroll
            for (int j = 0; j < 4; ++j) {
                int r = wr*128 + mi*16 + lg*4 + j;
                int c = wc*64 + ni*16 + lr;
                Dst[r*256 + c] = f2bf(acc[mi][ni][j]);
            }

    if (bid == 0) {
        // a1[o] = sum_k Ww[o][k] gb[k]
        if (t < 256) {
            float s = 0.f;
            #pragma unroll
            for (int q = 0; q < 32; ++q) {
                float4 f = *(const float4*)(Wwf + (size_t)t*128 + q*4);
                s += f.x*gbv[q*4] + f.y*gbv[q*4+1] + f.z*gbv[q*4+2] + f.w*gbv[q*4+3];
            }
            a1[t] = s;
        }
    } else {
        // c1v[c'] = sum_k Tw[k][c'] pb[k];  p2[c1] = sum_k Pw[k][c1] tb[k]
        if (t < 256) {
            float s1 = 0.f, s2 = 0.f;
            for (int k = 0; k < 128; ++k) {
                s1 += twf[(size_t)k*256 + t] * pbv[k];
                s2 += pwf[(size_t)k*256 + t] * tbv[k];
            }
            c1v[t] = s1; p2[t] = s2;
        }
        if (t < 64) {
            float v = pbv[t]*tbv[t] + pbv[t+64]*tbv[t+64];
            #pragma unroll
            for (int off = 1; off < 64; off <<= 1) v += __shfl_xor(v, off);
            if (t == 0) params[0] = v;
        }
    }
}

// ============ kE: 32 blocks (b, o-slice of 64). Y=A_sl*S; E=(Y*Cm)/N + rank-2; f; BN stats ============
__global__ __launch_bounds__(512) void kE(
    const unsigned short* __restrict__ Sp, const float* __restrict__ Rp,
    const unsigned short* __restrict__ Abf, const unsigned short* __restrict__ CmT,
    const float* __restrict__ a1g, const float* __restrict__ c1vg, const float* __restrict__ p2g,
    const float* __restrict__ params, const float* __restrict__ Wbv,
    unsigned short* __restrict__ Ebf, float* __restrict__ fv, float* __restrict__ stats)
{
    __shared__ __align__(16) unsigned short Ybuf[16384];  // [64][256] swz
    __shared__ __align__(16) unsigned short Ebuf[16384];  // [64][256] swz
    __shared__ float r_l[256], p2_l[256], c1v_l[256], cr[256];
    __shared__ float a1_l[64], ar[64], Yp2[64], er[64], diag_l[64];
    __shared__ float rp2_s;
    int blk = blockIdx.x;
    int b = blk >> 2, obase = (blk & 3) * 64;
    int t = threadIdx.x, lane = t & 63, wv = t >> 6;
    int lr = lane & 15, lg = lane >> 4;
    const float invN = 1.0f/4096.0f;

    // ph0: vector loads + r reduce
    if (t < 256) {
        float s = 0.f;
        #pragma unroll
        for (int i = 0; i < 16; ++i) s += Rp[(b*16 + i)*256 + t];
        r_l[t] = s;
        p2_l[t] = p2g[t];
        c1v_l[t] = c1vg[t];
    } else if (t < 320) {
        a1_l[t - 256] = a1g[obase + (t - 256)];
    }
    __syncthreads();

    // GEMM1: Y[64][256] = sum_i A_sl * Sp_i
    f32x4 acc[4][2];
    #pragma unroll
    for (int i = 0; i < 4; ++i) { acc[i][0] = (f32x4){0,0,0,0}; acc[i][1] = (f32x4){0,0,0,0}; }
    const unsigned short* Arow0 = Abf + (size_t)obase*256;
    for (int i = 0; i < 16; ++i) {
        const unsigned short* Spb = Sp + (size_t)(b*16 + i)*65536;
        #pragma unroll
        for (int ks = 0; ks < 8; ++ks) {
            bf16x8 a4[4], b2[2];
            #pragma unroll
            for (int mi = 0; mi < 4; ++mi)
                a4[mi] = __builtin_bit_cast(bf16x8, *(const u16x8*)(Arow0 + (size_t)(mi*16+lr)*256 + ks*32 + lg*8));
            #pragma unroll
            for (int ni = 0; ni < 2; ++ni)
                b2[ni] = __builtin_bit_cast(bf16x8, *(const u16x8*)(Spb + (size_t)(wv*32+ni*16+lr)*256 + ks*32 + lg*8));
            #pragma unroll
            for (int mi = 0; mi < 4; ++mi)
                #pragma unroll
                for (int ni = 0; ni < 2; ++ni)
                    acc[mi][ni] = MFMA(a4[mi], b2[ni], acc[mi][ni]);
        }
    }
    #pragma unroll
    for (int mi = 0; mi < 4; ++mi)
        #pragma unroll
        for (int ni = 0; ni < 2; ++ni)
            #pragma unroll
            for (int j = 0; j < 4; ++j) {
                int ol = mi*16 + lg*4 + j;
                int c2 = wv*32 + ni*16 + lr;
                Ybuf[ol*256 + (c2 ^ ((ol&7)<<3))] = f2bf(acc[mi][ni][j]);
            }
    __syncthreads();

    // ph1b: ar[o]=A.r, Yp2[o]=Y.p2, cr[c']=CmT.r, rp2
    {
        int row = t >> 3, p8 = t & 7;
        float sA = 0.f, sY = 0.f;
        const unsigned short* Ar = Abf + (size_t)(obase + row)*256 + p8*32;
        #pragma unroll
        for (int q = 0; q < 4; ++q) {
            u16x8 av = *(const u16x8*)(Ar + q*8);
            #pragma unroll
            for (int e = 0; e < 8; ++e) {
                int c = p8*32 + q*8 + e;
                sA += bf2f(av[e]) * r_l[c];
                sY += bf2f(Ybuf[row*256 + (c ^ ((row&7)<<3))]) * p2_l[c];
            }
        }
        sA += __shfl_xor(sA, 1); sA += __shfl_xor(sA, 2); sA += __shfl_xor(sA, 4);
        sY += __shfl_xor(sY, 1); sY += __shfl_xor(sY, 2); sY += __shfl_xor(sY, 4);
        if (p8 == 0) { ar[row] = sA; Yp2[row] = sY; }
    }
    if (t < 256) {
        float s = 0.f;
        const unsigned short* Cr = CmT + (size_t)t*256;
        #pragma unroll
        for (int q = 0; q < 32; ++q) {
            u16x8 v = *(const u16x8*)(Cr + q*8);
            #pragma unroll
            for (int e = 0; e < 8; ++e) s += bf2f(v[e]) * r_l[q*8 + e];
        }
        cr[t] = s;
    }
    if (t < 64) {
        float v = r_l[t*4]*p2_l[t*4] + r_l[t*4+1]*p2_l[t*4+1]
                + r_l[t*4+2]*p2_l[t*4+2] + r_l[t*4+3]*p2_l[t*4+3];
        #pragma unroll
        for (int off = 1; off < 64; off <<= 1) v += __shfl_xor(v, off);
        if (t == 0) rp2_s = v;
    }
    __syncthreads();

    // GEMM2: E = (Y*Cm)/N + a1*cr^T/N + (ar/N + a1)*c1v^T
    f32x4 accE[4][2];
    #pragma unroll
    for (int i = 0; i < 4; ++i) { accE[i][0] = (f32x4){0,0,0,0}; accE[i][1] = (f32x4){0,0,0,0}; }
    #pragma unroll
    for (int ks = 0; ks < 8; ++ks) {
        bf16x8 a4[4], b2[2];
        #pragma unroll
        for (int mi = 0; mi < 4; ++mi) {
            int ol = mi*16 + lr;
            a4[mi] = __builtin_bit_cast(bf16x8, *(const u16x8*)&Ybuf[ol*256 + ((ks*32 + lg*8) ^ ((ol&7)<<3))]);
        }
        #pragma unroll
        for (int ni = 0; ni < 2; ++ni)
            b2[ni] = __builtin_bit_cast(bf16x8, *(const u16x8*)(CmT + (size_t)(wv*32+ni*16+lr)*256 + ks*32 + lg*8));
        #pragma unroll
        for (int mi = 0; mi < 4; ++mi)
            #pragma unroll
            for (int ni = 0; ni < 2; ++ni)
                accE[mi][ni] = MFMA(a4[mi], b2[ni], accE[mi][ni]);
    }
    unsigned short* Eb = Ebf + (size_t)b*65536;
    #pragma unroll
    for (int mi = 0; mi < 4; ++mi)
        #pragma unroll
        for (int ni = 0; ni < 2; ++ni)
            #pragma unroll
            for (int j = 0; j < 4; ++j) {
                int ol = mi*16 + lg*4 + j;
                int cp = wv*32 + ni*16 + lr;
                float e = accE[mi][ni][j]*invN + a1_l[ol]*invN*cr[cp]
                        + (invN*ar[ol] + a1_l[ol])*c1v_l[cp];
                unsigned short eb = f2bf(e);
                Ebuf[ol*256 + (cp ^ ((ol&7)<<3))] = eb;
                Eb[(size_t)(obase + ol)*256 + cp] = eb;
            }
    __syncthreads();

    // ph2b: er[o] = E.r ; f ; zero diag
    float f_reg = 0.f;
    {
        int row = t >> 3, p8 = t & 7;
        float s = 0.f;
        #pragma unroll
        for (int q = 0; q < 4; ++q)
            #pragma unroll
            for (int e = 0; e < 8; ++e) {
                int c = p8*32 + q*8 + e;
                s += bf2f(Ebuf[row*256 + (c ^ ((row&7)<<3))]) * r_l[c];
            }
        s += __shfl_xor(s, 1); s += __shfl_xor(s, 2); s += __shfl_xor(s, 4);
        if (p8 == 0) er[row] = s;
    }
    if (t < 64) {
        diag_l[t] = 0.f;
        float sg = params[0];
        f_reg = invN*(Yp2[t] + a1_l[t]*rp2_s + ar[t]*sg) + a1_l[t]*sg + Wbv[obase + t];
        fv[b*256 + obase + t] = f_reg;
    }
    __syncthreads();

    // GEMM3: Z = sum_i E_sl * Sp_i ; diag[o] = sum_c2 Z[o][c2]*E[o][c2]
    f32x4 accZ[4][2];
    #pragma unroll
    for (int i = 0; i < 4; ++i) { accZ[i][0] = (f32x4){0,0,0,0}; accZ[i][1] = (f32x4){0,0,0,0}; }
    for (int i = 0; i < 16; ++i) {
        const unsigned short* Spb = Sp + (size_t)(b*16 + i)*65536;
        #pragma unroll
        for (int ks = 0; ks < 8; ++ks) {
            bf16x8 a4[4], b2[2];
            #pragma unroll
            for (int mi = 0; mi < 4; ++mi) {
                int ol = mi*16 + lr;
                a4[mi] = __builtin_bit_cast(bf16x8, *(const u16x8*)&Ebuf[ol*256 + ((ks*32 + lg*8) ^ ((ol&7)<<3))]);
            }
            #pragma unroll
            for (int ni = 0; ni < 2; ++ni)
                b2[ni] = __builtin_bit_cast(bf16x8, *(const u16x8*)(Spb + (size_t)(wv*32+ni*16+lr)*256 + ks*32 + lg*8));
            #pragma unroll
            for (int mi = 0; mi < 4; ++mi)
                #pragma unroll
                for (int ni = 0; ni < 2; ++ni)
                    accZ[mi][ni] = MFMA(a4[mi], b2[ni], accZ[mi][ni]);
        }
    }
    #pragma unroll
    for (int mi = 0; mi < 4; ++mi)
        #pragma unroll
        for (int j = 0; j < 4; ++j) {
            int ol = mi*16 + lg*4 + j;
            float s = 0.f;
            #pragma unroll
            for (int ni = 0; ni < 2; ++ni) {
                int c2 = wv*32 + ni*16 + lr;
                s += accZ[mi][ni][j] * bf2f(Ebuf[ol*256 + (c2 ^ ((ol&7)<<3))]);
            }
            s += __shfl_xor(s, 1); s += __shfl_xor(s, 2);
            s += __shfl_xor(s, 4); s += __shfl_xor(s, 8);
            if (lr == 0) atomicAdd(&diag_l[ol], s);
        }
    __syncthreads();

    if (t < 64) {
        int o = obase + t;
        atomicAdd(&stats[o], er[t] + 4096.0f*f_reg);
        atomicAdd(&stats[256 + o], diag_l[t] + 2.0f*f_reg*er[t] + 4096.0f*f_reg*f_reg);
    }
}

// ============ kF: out = (E x + f - mu)*gamma*rsqrt(var+eps) + beta + x ============
__global__ __launch_bounds__(512) void kF(
    const float* __restrict__ x, const unsigned short* __restrict__ Ebf,
    const float* __restrict__ fv, const float* __restrict__ stats,
    const float* __restrict__ gamma, const float* __restrict__ beta,
    float* __restrict__ out)
{
    __shared__ __align__(16) unsigned short Xs[128*256];  // 64 KB, [n][c] swz
    __shared__ float scale_l[256], shift_l[256];
    int b = blockIdx.x >> 5, n0 = (blockIdx.x & 31) * 128;
    int t = threadIdx.x, lane = t & 63, wv = t >> 6, lr = lane & 15, lg = lane >> 4;
    const float inv = 1.0f / 32768.0f;
    if (t < 256) {
        float mu  = stats[t] * inv;
        float var = stats[256 + t] * inv - mu*mu;
        float sc  = gamma[t] * rsqrtf(var + 1e-5f);
        scale_l[t] = sc;
        shift_l[t] = (fv[b*256 + t] - mu) * sc + beta[t];
    }
    {
        int nq = (t & 31) * 4, c0 = (t >> 5) * 4;
        const float* xb = x + (size_t)b*CIN*NN + n0 + nq;
        #pragma unroll
        for (int p = 0; p < 4; ++p) {
            int c = p*64 + c0;
            const float* xp = xb + (size_t)c*NN;
            float4 f0 = *(const float4*)(xp);
            float4 f1 = *(const float4*)(xp + NN);
            float4 f2 = *(const float4*)(xp + 2*NN);
            float4 f3 = *(const float4*)(xp + 3*NN);
            *(ushort4*)&Xs[(nq+0)*256 + (c ^ (((nq+0)&7)<<3))] = pack4(f0.x,f1.x,f2.x,f3.x);
            *(ushort4*)&Xs[(nq+1)*256 + (c ^ (((nq+1)&7)<<3))] = pack4(f0.y,f1.y,f2.y,f3.y);
            *(ushort4*)&Xs[(nq+2)*256 + (c ^ (((nq+2)&7)<<3))] = pack4(f0.z,f1.z,f2.z,f3.z);
            *(ushort4*)&Xs[(nq+3)*256 + (c ^ (((nq+3)&7)<<3))] = pack4(f0.w,f1.w,f2.w,f3.w);
        }
    }
    __syncthreads();

    int wn = wv >> 2, wo = wv & 3;
    int nb = wn*64, ob = wo*64;
    const unsigned short* Eb = Ebf + (size_t)b*65536;
    f32x4 acc[4][4];
    #pragma unroll
    for (int i = 0; i < 4; ++i)
        #pragma unroll
        for (int j = 0; j < 4; ++j) acc[i][j] = (f32x4){0,0,0,0};

    #pragma unroll
    for (int ks = 0; ks < 8; ++ks) {
        bf16x8 xf[4], ef[4];
        #pragma unroll
        for (int ni = 0; ni < 4; ++ni) {
            int n = nb + ni*16 + lr;
            xf[ni] = __builtin_bit_cast(bf16x8, *(const u16x8*)&Xs[(n*256 + ks*32 + lg*8) ^ ((n&7)<<3)]);
        }
        #pragma unroll
        for (int oi = 0; oi < 4; ++oi) {
            int o = ob + oi*16 + lr;
            ef[oi] = __builtin_bit_cast(bf16x8, *(const u16x8*)(Eb + (size_t)o*256 + ks*32 + lg*8));
        }
        #pragma unroll
        for (int ni = 0; ni < 4; ++ni)
            #pragma unroll
            for (int oi = 0; oi < 4; ++oi)
                acc[ni][oi] = MFMA(xf[ni], ef[oi], acc[ni][oi]);
    }

    float* op = out + (size_t)b*CIN*NN;
    #pragma unroll
    for (int oi = 0; oi < 4; ++oi) {
        int o = ob + oi*16 + lr;
        float sc = scale_l[o], sh = shift_l[o];
        #pragma unroll
        for (int ni = 0; ni < 4; ++ni) {
            int nbase = nb + ni*16 + lg*4;
            float4 st;
            float* sp_ = &st.x;
            #pragma unroll
            for (int j = 0; j < 4; ++j) {
                int n = nbase + j;
                sp_[j] = acc[ni][oi][j]*sc + sh + bf2f(Xs[(n*256 + o) ^ ((n&7)<<3)]);
            }
            *(float4*)(op + (size_t)o*NN + n0 + nbase) = st;
        }
    }
}

extern "C" void kernel_launch(void* const* d_in, const int* in_sizes, int n_in,
                              void* d_out, int out_size, void* d_ws, size_t ws_size,
                              hipStream_t stream)
{
    (void)in_sizes; (void)n_in; (void)out_size; (void)ws_size;
    const float* x     = (const float*)d_in[0];
    const float* gw    = (const float*)d_in[1];
    const float* gb    = (const float*)d_in[2];
    const float* tw    = (const float*)d_in[3];
    const float* tb    = (const float*)d_in[4];
    const float* pw    = (const float*)d_in[5];
    const float* pb    = (const float*)d_in[6];
    const float* Ww    = (const float*)d_in[7];
    const float* Wb    = (const float*)d_in[8];
    const float* gamma = (const float*)d_in[9];
    const float* beta  = (const float*)d_in[10];
    float* out = (float*)d_out;

    char* ws = (char*)d_ws;
    unsigned short* Sp  = (unsigned short*)(ws + 0);          // 16 MB
    float* Rp           = (float*)(ws + 16777216);            // 128 KB
    unsigned short* Abf = (unsigned short*)(ws + 16908288);   // 128 KB
    unsigned short* CmT = (unsigned short*)(ws + 17039360);   // 128 KB
    unsigned short* Ebf = (unsigned short*)(ws + 17170432);   // 1 MB
    float* fv           = (float*)(ws + 18219008);            // 8 KB
    float* a1           = (float*)(ws + 18227200);            // 1 KB
    float* c1v          = (float*)(ws + 18228224);            // 1 KB
    float* p2           = (float*)(ws + 18229248);            // 1 KB
    float* params       = (float*)(ws + 18230272);            // 64 B
    float* stats        = (float*)(ws + 18230336);            // 2 KB

    kA<<<128, 512, 0, stream>>>(x, gw, tw, pw, gb, pb, tb, Sp, Rp, Abf, CmT, a1, c1v, p2, params, stats);
    kP<<<2,   512, 0, stream>>>(Ww, gw, tw, pw, gb, pb, tb, Abf, CmT, a1, c1v, p2, params, stats);
    kE<<<32,  512, 0, stream>>>(Sp, Rp, Abf, CmT, a1, c1v, p2, params, Wb, Ebf, fv, stats);
    kF<<<256, 512, 0, stream>>>(x, Ebf, fv, stats, gamma, beta, out);
}

// Round 6
// 100.790 us; speedup vs baseline: 2.0153x; 2.0153x over previous
//
#include <hip/hip_runtime.h>
#include <hip/hip_bf16.h>
#include <stdint.h>

#define BB   8
#define CIN  256
#define COUT 128
#define NN   4096

using f32x4  = __attribute__((ext_vector_type(4))) float;
using bf16x8 = __attribute__((ext_vector_type(8))) __bf16;
using u16x8  = __attribute__((ext_vector_type(8))) unsigned short;

static __device__ __forceinline__ unsigned short f2bf(float f) {
    unsigned int u = __builtin_bit_cast(unsigned int, f);
    u += 0x7FFFu + ((u >> 16) & 1u);
    return (unsigned short)(u >> 16);
}
static __device__ __forceinline__ float bf2f(unsigned short u) {
    return __builtin_bit_cast(float, (unsigned int)u << 16);
}
static __device__ __forceinline__ ushort4 pack4(float a, float b, float c, float d) {
    ushort4 r; r.x=f2bf(a); r.y=f2bf(b); r.z=f2bf(c); r.w=f2bf(d); return r;
}
#define MFMA(a,b,c) __builtin_amdgcn_mfma_f32_16x16x32_bf16((a),(b),(c),0,0,0)

static __device__ __forceinline__ int sw256(int r, int c) { return (r*256 + c) ^ ((r&7)<<3); }
static __device__ __forceinline__ int sw128(int r, int c) { return (r*128 + c) ^ ((r&7)<<3); }

// ============ kA: 128 blocks. Gram partials Sp[bid] (bf16) = X_chunk X_chunk^T, row-sum partials Rp ============
__global__ __launch_bounds__(512) void kA(
    const float* __restrict__ x,
    unsigned short* __restrict__ Sp, float* __restrict__ Rp)
{
    __shared__ __align__(16) unsigned short SH[65536];   // 128 KB, [c][n256] swz
    int bid = blockIdx.x;
    int b = bid >> 4, ch = bid & 15;
    int n0 = ch * 256;
    int t = threadIdx.x, lane = t & 63, wv = t >> 6;
    int lr = lane & 15, lg = lane >> 4;

    const float* xb = x + (size_t)b*CIN*NN + n0;
    #pragma unroll
    for (int i = 0; i < 32; ++i) {
        int c = wv*32 + i;
        float4 f = *(const float4*)(xb + (size_t)c*NN + lane*4);
        float s = f.x + f.y + f.z + f.w;
        #pragma unroll
        for (int off = 1; off < 64; off <<= 1) s += __shfl_xor(s, off);
        if (lane == 0) Rp[bid*256 + c] = s;
        *(ushort4*)&SH[sw256(c, lane*4)] = pack4(f.x, f.y, f.z, f.w);
    }
    __syncthreads();

    int wr = wv >> 1, wc = wv & 1;      // 4x2: tile 64 x 128
    f32x4 acc[4][8];
    #pragma unroll
    for (int i = 0; i < 4; ++i)
        #pragma unroll
        for (int j = 0; j < 8; ++j) acc[i][j] = (f32x4){0.f,0.f,0.f,0.f};
    #pragma unroll
    for (int ks = 0; ks < 8; ++ks) {
        bf16x8 af[4], bfr[8];
        #pragma unroll
        for (int mi = 0; mi < 4; ++mi) {
            int row = wr*64 + mi*16 + lr;
            af[mi] = __builtin_bit_cast(bf16x8, *(const u16x8*)&SH[sw256(row, ks*32 + lg*8)]);
        }
        #pragma unroll
        for (int ni = 0; ni < 8; ++ni) {
            int row = wc*128 + ni*16 + lr;
            bfr[ni] = __builtin_bit_cast(bf16x8, *(const u16x8*)&SH[sw256(row, ks*32 + lg*8)]);
        }
        #pragma unroll
        for (int mi = 0; mi < 4; ++mi)
            #pragma unroll
            for (int ni = 0; ni < 8; ++ni)
                acc[mi][ni] = MFMA(af[mi], bfr[ni], acc[mi][ni]);
    }
    unsigned short* dst = Sp + (size_t)bid * 65536;
    #pragma unroll
    for (int mi = 0; mi < 4; ++mi)
        #pragma unroll
        for (int ni = 0; ni < 8; ++ni)
            #pragma unroll
            for (int j = 0; j < 4; ++j) {
                int c1 = wr*64 + mi*16 + lg*4 + j;
                int c2 = wc*128 + ni*16 + lr;
                dst[c1*256 + c2] = f2bf(acc[mi][ni][j]);
            }
}

// ============ kRP: 138 blocks.
//   0-127 : Sbf[b] = sum of 16 bf16 partials (fp32 accumulate)
//   128-135: rv[b] = sum of Rp partials
//   136   : Abf = Ww*Gw (bf16), a1 = Ww*gb, zero stats
//   137   : CmT = Tw^T*Pw (bf16), c1v = Tw^T*pb, p2 = Pw^T*tb, sigma ============
__global__ __launch_bounds__(512) void kRP(
    const unsigned short* __restrict__ Sp, const float* __restrict__ Rp,
    const float* __restrict__ Wwf, const float* __restrict__ gwf,
    const float* __restrict__ twf, const float* __restrict__ pwf,
    const float* __restrict__ gbv, const float* __restrict__ pbv, const float* __restrict__ tbv,
    unsigned short* __restrict__ Sbf, float* __restrict__ rv,
    unsigned short* __restrict__ Abf, unsigned short* __restrict__ CmT,
    float* __restrict__ a1, float* __restrict__ c1v, float* __restrict__ p2,
    float* __restrict__ params, float* __restrict__ stats)
{
    __shared__ __align__(16) unsigned short Ls[32768];   // 64 KB
    __shared__ __align__(16) unsigned short Rs[32768];   // 64 KB
    int bid = blockIdx.x;
    int t = threadIdx.x, lane = t & 63, wv = t >> 6;
    int lr = lane & 15, lg = lane >> 4;

    if (bid < 128) {
        int b = bid >> 4, sl = bid & 15;
        int base = sl*4096 + t*8;
        float s[8] = {0.f,0.f,0.f,0.f,0.f,0.f,0.f,0.f};
        #pragma unroll
        for (int i = 0; i < 16; ++i) {
            u16x8 v = *(const u16x8*)(Sp + (size_t)(b*16 + i)*65536 + base);
            #pragma unroll
            for (int e = 0; e < 8; ++e) s[e] += bf2f(v[e]);
        }
        u16x8 o;
        #pragma unroll
        for (int e = 0; e < 8; ++e) o[e] = f2bf(s[e]);
        *(u16x8*)(Sbf + (size_t)b*65536 + base) = o;
        return;
    }
    if (bid < 136) {
        int b = bid - 128;
        if (t < 256) {
            float s = 0.f;
            #pragma unroll
            for (int i = 0; i < 16; ++i) s += Rp[(b*16 + i)*256 + t];
            rv[b*256 + t] = s;
        }
        return;
    }

    if (bid == 136) {
        // Ls = Ww [256][128] row-major
        for (int i = t; i < 8192; i += 512) {
            int flat = i*4, r = flat >> 7, c = flat & 127;
            float4 f = *(const float4*)(Wwf + flat);
            *(ushort4*)&Ls[sw128(r, c)] = pack4(f.x, f.y, f.z, f.w);
        }
        // Rs = Gw^T : Rs[c][k]
        {
            int c = lane * 4;  int k4 = wv * 4;
            #pragma unroll
            for (int rep = 0; rep < 4; ++rep) {
                int kb = rep*32 + k4;
                float4 f0 = *(const float4*)(gwf + (size_t)(kb+0)*256 + c);
                float4 f1 = *(const float4*)(gwf + (size_t)(kb+1)*256 + c);
                float4 f2 = *(const float4*)(gwf + (size_t)(kb+2)*256 + c);
                float4 f3 = *(const float4*)(gwf + (size_t)(kb+3)*256 + c);
                *(ushort4*)&Rs[sw128(c+0, kb)] = pack4(f0.x, f1.x, f2.x, f3.x);
                *(ushort4*)&Rs[sw128(c+1, kb)] = pack4(f0.y, f1.y, f2.y, f3.y);
                *(ushort4*)&Rs[sw128(c+2, kb)] = pack4(f0.z, f1.z, f2.z, f3.z);
                *(ushort4*)&Rs[sw128(c+3, kb)] = pack4(f0.w, f1.w, f2.w, f3.w);
            }
        }
        if (t < 512) stats[t] = 0.f;
    } else {
        // Ls = Tw^T [c'][k], Rs = Pw^T [c1][k]
        {
            int c = lane * 4;  int k4 = wv * 4;
            #pragma unroll
            for (int rep = 0; rep < 4; ++rep) {
                int kb = rep*32 + k4;
                float4 f0 = *(const float4*)(twf + (size_t)(kb+0)*256 + c);
                float4 f1 = *(const float4*)(twf + (size_t)(kb+1)*256 + c);
                float4 f2 = *(const float4*)(twf + (size_t)(kb+2)*256 + c);
                float4 f3 = *(const float4*)(twf + (size_t)(kb+3)*256 + c);
                *(ushort4*)&Ls[sw128(c+0, kb)] = pack4(f0.x, f1.x, f2.x, f3.x);
                *(ushort4*)&Ls[sw128(c+1, kb)] = pack4(f0.y, f1.y, f2.y, f3.y);
                *(ushort4*)&Ls[sw128(c+2, kb)] = pack4(f0.z, f1.z, f2.z, f3.z);
                *(ushort4*)&Ls[sw128(c+3, kb)] = pack4(f0.w, f1.w, f2.w, f3.w);
                float4 g0 = *(const float4*)(pwf + (size_t)(kb+0)*256 + c);
                float4 g1 = *(const float4*)(pwf + (size_t)(kb+1)*256 + c);
                float4 g2 = *(const float4*)(pwf + (size_t)(kb+2)*256 + c);
                float4 g3 = *(const float4*)(pwf + (size_t)(kb+3)*256 + c);
                *(ushort4*)&Rs[sw128(c+0, kb)] = pack4(g0.x, g1.x, g2.x, g3.x);
                *(ushort4*)&Rs[sw128(c+1, kb)] = pack4(g0.y, g1.y, g2.y, g3.y);
                *(ushort4*)&Rs[sw128(c+2, kb)] = pack4(g0.z, g1.z, g2.z, g3.z);
                *(ushort4*)&Rs[sw128(c+3, kb)] = pack4(g0.w, g1.w, g2.w, g3.w);
            }
        }
    }
    __syncthreads();

    // GEMM: D[r][c] = sum_k Ls[r][k] * Rs[c][k], out 256x256, K=128
    int wr = wv >> 2, wc = wv & 3;      // 2x4: tile 128 x 64
    f32x4 acc[8][4];
    #pragma unroll
    for (int i = 0; i < 8; ++i)
        #pragma unroll
        for (int j = 0; j < 4; ++j) acc[i][j] = (f32x4){0.f,0.f,0.f,0.f};
    #pragma unroll
    for (int ks = 0; ks < 4; ++ks) {
        bf16x8 af[8], bfr[4];
        #pragma unroll
        for (int mi = 0; mi < 8; ++mi) {
            int r = wr*128 + mi*16 + lr;
            af[mi] = __builtin_bit_cast(bf16x8, *(const u16x8*)&Ls[sw128(r, ks*32 + lg*8)]);
        }
        #pragma unroll
        for (int ni = 0; ni < 4; ++ni) {
            int c = wc*64 + ni*16 + lr;
            bfr[ni] = __builtin_bit_cast(bf16x8, *(const u16x8*)&Rs[sw128(c, ks*32 + lg*8)]);
        }
        #pragma unroll
        for (int mi = 0; mi < 8; ++mi)
            #pragma unroll
            for (int ni = 0; ni < 4; ++ni)
                acc[mi][ni] = MFMA(af[mi], bfr[ni], acc[mi][ni]);
    }
    unsigned short* Dst = (bid == 136) ? Abf : CmT;
    #pragma unroll
    for (int mi = 0; mi < 8; ++mi)
        #pragma unroll
        for (int ni = 0; ni < 4; ++ni)
            #pragma unroll
            for (int j = 0; j < 4; ++j) {
                int r = wr*128 + mi*16 + lg*4 + j;
                int c = wc*64 + ni*16 + lr;
                Dst[r*256 + c] = f2bf(acc[mi][ni][j]);
            }

    if (bid == 136) {
        if (t < 256) {
            float s = 0.f;
            #pragma unroll
            for (int q = 0; q < 32; ++q) {
                float4 f = *(const float4*)(Wwf + (size_t)t*128 + q*4);
                s += f.x*gbv[q*4] + f.y*gbv[q*4+1] + f.z*gbv[q*4+2] + f.w*gbv[q*4+3];
            }
            a1[t] = s;
        }
    } else {
        if (t < 256) {
            float s1 = 0.f, s2 = 0.f;
            for (int k = 0; k < 128; ++k) {
                s1 += twf[(size_t)k*256 + t] * pbv[k];
                s2 += pwf[(size_t)k*256 + t] * tbv[k];
            }
            c1v[t] = s1; p2[t] = s2;
        }
        if (t < 64) {
            float v = pbv[t]*tbv[t] + pbv[t+64]*tbv[t+64];
            #pragma unroll
            for (int off = 1; off < 64; off <<= 1) v += __shfl_xor(v, off);
            if (t == 0) params[0] = v;
        }
    }
}

// ============ kE: 32 blocks (b, o-slice of 64). Y=A_sl*S; E=(Y*Cm)/N + rank-2; f; BN stats ============
__global__ __launch_bounds__(512) void kE(
    const unsigned short* __restrict__ Sbf, const float* __restrict__ rv,
    const unsigned short* __restrict__ Abf, const unsigned short* __restrict__ CmT,
    const float* __restrict__ a1g, const float* __restrict__ c1vg, const float* __restrict__ p2g,
    const float* __restrict__ params, const float* __restrict__ Wbv,
    unsigned short* __restrict__ Ebf, float* __restrict__ fv, float* __restrict__ stats)
{
    __shared__ __align__(16) unsigned short Ybuf[16384];  // [64][256] swz
    __shared__ __align__(16) unsigned short Ebuf[16384];  // [64][256] swz
    __shared__ float r_l[256], p2_l[256], c1v_l[256], cr[256];
    __shared__ float a1_l[64], ar[64], Yp2[64], er[64], diag_l[64];
    __shared__ float rp2_s;
    int blk = blockIdx.x;
    int b = blk >> 2, obase = (blk & 3) * 64;
    int t = threadIdx.x, lane = t & 63, wv = t >> 6;
    int lr = lane & 15, lg = lane >> 4;
    const float invN = 1.0f/4096.0f;
    const unsigned short* Sb = Sbf + (size_t)b*65536;

    if (t < 256) {
        r_l[t] = rv[b*256 + t];
        p2_l[t] = p2g[t];
        c1v_l[t] = c1vg[t];
    } else if (t < 320) {
        a1_l[t - 256] = a1g[obase + (t - 256)];
    }
    __syncthreads();

    // GEMM1: Y[64][256] = A_sl * S   (K=256; S symmetric)
    f32x4 acc[4][2];
    #pragma unroll
    for (int i = 0; i < 4; ++i) { acc[i][0] = (f32x4){0,0,0,0}; acc[i][1] = (f32x4){0,0,0,0}; }
    const unsigned short* Arow0 = Abf + (size_t)obase*256;
    #pragma unroll
    for (int ks = 0; ks < 8; ++ks) {
        bf16x8 a4[4], b2[2];
        #pragma unroll
        for (int mi = 0; mi < 4; ++mi)
            a4[mi] = __builtin_bit_cast(bf16x8, *(const u16x8*)(Arow0 + (size_t)(mi*16+lr)*256 + ks*32 + lg*8));
        #pragma unroll
        for (int ni = 0; ni < 2; ++ni)
            b2[ni] = __builtin_bit_cast(bf16x8, *(const u16x8*)(Sb + (size_t)(wv*32+ni*16+lr)*256 + ks*32 + lg*8));
        #pragma unroll
        for (int mi = 0; mi < 4; ++mi)
            #pragma unroll
            for (int ni = 0; ni < 2; ++ni)
                acc[mi][ni] = MFMA(a4[mi], b2[ni], acc[mi][ni]);
    }
    #pragma unroll
    for (int mi = 0; mi < 4; ++mi)
        #pragma unroll
        for (int ni = 0; ni < 2; ++ni)
            #pragma unroll
            for (int j = 0; j < 4; ++j) {
                int ol = mi*16 + lg*4 + j;
                int c2 = wv*32 + ni*16 + lr;
                Ybuf[ol*256 + (c2 ^ ((ol&7)<<3))] = f2bf(acc[mi][ni][j]);
            }
    __syncthreads();

    // ph1b: ar[o]=A.r, Yp2[o]=Y.p2, cr[c']=CmT.r, rp2
    {
        int row = t >> 3, p8 = t & 7;
        float sA = 0.f, sY = 0.f;
        const unsigned short* Ar = Abf + (size_t)(obase + row)*256 + p8*32;
        #pragma unroll
        for (int q = 0; q < 4; ++q) {
            u16x8 av = *(const u16x8*)(Ar + q*8);
            #pragma unroll
            for (int e = 0; e < 8; ++e) {
                int c = p8*32 + q*8 + e;
                sA += bf2f(av[e]) * r_l[c];
                sY += bf2f(Ybuf[row*256 + (c ^ ((row&7)<<3))]) * p2_l[c];
            }
        }
        sA += __shfl_xor(sA, 1); sA += __shfl_xor(sA, 2); sA += __shfl_xor(sA, 4);
        sY += __shfl_xor(sY, 1); sY += __shfl_xor(sY, 2); sY += __shfl_xor(sY, 4);
        if (p8 == 0) { ar[row] = sA; Yp2[row] = sY; }
    }
    if (t < 256) {
        float s = 0.f;
        const unsigned short* Cr = CmT + (size_t)t*256;
        #pragma unroll
        for (int q = 0; q < 32; ++q) {
            u16x8 v = *(const u16x8*)(Cr + q*8);
            #pragma unroll
            for (int e = 0; e < 8; ++e) s += bf2f(v[e]) * r_l[q*8 + e];
        }
        cr[t] = s;
    }
    if (t < 64) {
        float v = r_l[t*4]*p2_l[t*4] + r_l[t*4+1]*p2_l[t*4+1]
                + r_l[t*4+2]*p2_l[t*4+2] + r_l[t*4+3]*p2_l[t*4+3];
        #pragma unroll
        for (int off = 1; off < 64; off <<= 1) v += __shfl_xor(v, off);
        if (t == 0) rp2_s = v;
    }
    __syncthreads();

    // GEMM2: E = (Y*Cm)/N + a1*cr^T/N + (ar/N + a1)*c1v^T
    f32x4 accE[4][2];
    #pragma unroll
    for (int i = 0; i < 4; ++i) { accE[i][0] = (f32x4){0,0,0,0}; accE[i][1] = (f32x4){0,0,0,0}; }
    #pragma unroll
    for (int ks = 0; ks < 8; ++ks) {
        bf16x8 a4[4], b2[2];
        #pragma unroll
        for (int mi = 0; mi < 4; ++mi) {
            int ol = mi*16 + lr;
            a4[mi] = __builtin_bit_cast(bf16x8, *(const u16x8*)&Ybuf[ol*256 + ((ks*32 + lg*8) ^ ((ol&7)<<3))]);
        }
        #pragma unroll
        for (int ni = 0; ni < 2; ++ni)
            b2[ni] = __builtin_bit_cast(bf16x8, *(const u16x8*)(CmT + (size_t)(wv*32+ni*16+lr)*256 + ks*32 + lg*8));
        #pragma unroll
        for (int mi = 0; mi < 4; ++mi)
            #pragma unroll
            for (int ni = 0; ni < 2; ++ni)
                accE[mi][ni] = MFMA(a4[mi], b2[ni], accE[mi][ni]);
    }
    unsigned short* Eb = Ebf + (size_t)b*65536;
    #pragma unroll
    for (int mi = 0; mi < 4; ++mi)
        #pragma unroll
        for (int ni = 0; ni < 2; ++ni)
            #pragma unroll
            for (int j = 0; j < 4; ++j) {
                int ol = mi*16 + lg*4 + j;
                int cp = wv*32 + ni*16 + lr;
                float e = accE[mi][ni][j]*invN + a1_l[ol]*invN*cr[cp]
                        + (invN*ar[ol] + a1_l[ol])*c1v_l[cp];
                unsigned short eb = f2bf(e);
                Ebuf[ol*256 + (cp ^ ((ol&7)<<3))] = eb;
                Eb[(size_t)(obase + ol)*256 + cp] = eb;
            }
    __syncthreads();

    // ph2b: er[o] = E.r ; f
    float f_reg = 0.f;
    {
        int row = t >> 3, p8 = t & 7;
        float s = 0.f;
        #pragma unroll
        for (int q = 0; q < 4; ++q)
            #pragma unroll
            for (int e = 0; e < 8; ++e) {
                int c = p8*32 + q*8 + e;
                s += bf2f(Ebuf[row*256 + (c ^ ((row&7)<<3))]) * r_l[c];
            }
        s += __shfl_xor(s, 1); s += __shfl_xor(s, 2); s += __shfl_xor(s, 4);
        if (p8 == 0) er[row] = s;
    }
    if (t < 64) {
        diag_l[t] = 0.f;
        float sg = params[0];
        f_reg = invN*(Yp2[t] + a1_l[t]*rp2_s + ar[t]*sg) + a1_l[t]*sg + Wbv[obase + t];
        fv[b*256 + obase + t] = f_reg;
    }
    __syncthreads();

    // GEMM3: Z = E_sl * S ; diag[o] = sum_c2 Z[o][c2]*E[o][c2]
    f32x4 accZ[4][2];
    #pragma unroll
    for (int i = 0; i < 4; ++i) { accZ[i][0] = (f32x4){0,0,0,0}; accZ[i][1] = (f32x4){0,0,0,0}; }
    #pragma unroll
    for (int ks = 0; ks < 8; ++ks) {
        bf16x8 a4[4], b2[2];
        #pragma unroll
        for (int mi = 0; mi < 4; ++mi) {
            int ol = mi*16 + lr;
            a4[mi] = __builtin_bit_cast(bf16x8, *(const u16x8*)&Ebuf[ol*256 + ((ks*32 + lg*8) ^ ((ol&7)<<3))]);
        }
        #pragma unroll
        for (int ni = 0; ni < 2; ++ni)
            b2[ni] = __builtin_bit_cast(bf16x8, *(const u16x8*)(Sb + (size_t)(wv*32+ni*16+lr)*256 + ks*32 + lg*8));
        #pragma unroll
        for (int mi = 0; mi < 4; ++mi)
            #pragma unroll
            for (int ni = 0; ni < 2; ++ni)
                accZ[mi][ni] = MFMA(a4[mi], b2[ni], accZ[mi][ni]);
    }
    #pragma unroll
    for (int mi = 0; mi < 4; ++mi)
        #pragma unroll
        for (int j = 0; j < 4; ++j) {
            int ol = mi*16 + lg*4 + j;
            float s = 0.f;
            #pragma unroll
            for (int ni = 0; ni < 2; ++ni) {
                int c2 = wv*32 + ni*16 + lr;
                s += accZ[mi][ni][j] * bf2f(Ebuf[ol*256 + (c2 ^ ((ol&7)<<3))]);
            }
            s += __shfl_xor(s, 1); s += __shfl_xor(s, 2);
            s += __shfl_xor(s, 4); s += __shfl_xor(s, 8);
            if (lr == 0) atomicAdd(&diag_l[ol], s);
        }
    __syncthreads();

    if (t < 64) {
        int o = obase + t;
        atomicAdd(&stats[o], er[t] + 4096.0f*f_reg);
        atomicAdd(&stats[256 + o], diag_l[t] + 2.0f*f_reg*er[t] + 4096.0f*f_reg*f_reg);
    }
}

// ============ kF: out = (E x + f - mu)*gamma*rsqrt(var+eps) + beta + x ============
__global__ __launch_bounds__(512) void kF(
    const float* __restrict__ x, const unsigned short* __restrict__ Ebf,
    const float* __restrict__ fv, const float* __restrict__ stats,
    const float* __restrict__ gamma, const float* __restrict__ beta,
    float* __restrict__ out)
{
    __shared__ __align__(16) unsigned short Xs[128*256];  // 64 KB, [n][c] swz
    __shared__ float scale_l[256], shift_l[256];
    int b = blockIdx.x >> 5, n0 = (blockIdx.x & 31) * 128;
    int t = threadIdx.x, lane = t & 63, wv = t >> 6, lr = lane & 15, lg = lane >> 4;
    const float inv = 1.0f / 32768.0f;
    if (t < 256) {
        float mu  = stats[t] * inv;
        float var = stats[256 + t] * inv - mu*mu;
        float sc  = gamma[t] * rsqrtf(var + 1e-5f);
        scale_l[t] = sc;
        shift_l[t] = (fv[b*256 + t] - mu) * sc + beta[t];
    }
    {
        int nq = (t & 31) * 4, c0 = (t >> 5) * 4;
        const float* xb = x + (size_t)b*CIN*NN + n0 + nq;
        #pragma unroll
        for (int p = 0; p < 4; ++p) {
            int c = p*64 + c0;
            const float* xp = xb + (size_t)c*NN;
            float4 f0 = *(const float4*)(xp);
            float4 f1 = *(const float4*)(xp + NN);
            float4 f2 = *(const float4*)(xp + 2*NN);
            float4 f3 = *(const float4*)(xp + 3*NN);
            *(ushort4*)&Xs[(nq+0)*256 + (c ^ (((nq+0)&7)<<3))] = pack4(f0.x,f1.x,f2.x,f3.x);
            *(ushort4*)&Xs[(nq+1)*256 + (c ^ (((nq+1)&7)<<3))] = pack4(f0.y,f1.y,f2.y,f3.y);
            *(ushort4*)&Xs[(nq+2)*256 + (c ^ (((nq+2)&7)<<3))] = pack4(f0.z,f1.z,f2.z,f3.z);
            *(ushort4*)&Xs[(nq+3)*256 + (c ^ (((nq+3)&7)<<3))] = pack4(f0.w,f1.w,f2.w,f3.w);
        }
    }
    __syncthreads();

    int wn = wv >> 2, wo = wv & 3;
    int nb = wn*64, ob = wo*64;
    const unsigned short* Eb = Ebf + (size_t)b*65536;
    f32x4 acc[4][4];
    #pragma unroll
    for (int i = 0; i < 4; ++i)
        #pragma unroll
        for (int j = 0; j < 4; ++j) acc[i][j] = (f32x4){0,0,0,0};

    #pragma unroll
    for (int ks = 0; ks < 8; ++ks) {
        bf16x8 xf[4], ef[4];
        #pragma unroll
        for (int ni = 0; ni < 4; ++ni) {
            int n = nb + ni*16 + lr;
            xf[ni] = __builtin_bit_cast(bf16x8, *(const u16x8*)&Xs[(n*256 + ks*32 + lg*8) ^ ((n&7)<<3)]);
        }
        #pragma unroll
        for (int oi = 0; oi < 4; ++oi) {
            int o = ob + oi*16 + lr;
            ef[oi] = __builtin_bit_cast(bf16x8, *(const u16x8*)(Eb + (size_t)o*256 + ks*32 + lg*8));
        }
        #pragma unroll
        for (int ni = 0; ni < 4; ++ni)
            #pragma unroll
            for (int oi = 0; oi < 4; ++oi)
                acc[ni][oi] = MFMA(xf[ni], ef[oi], acc[ni][oi]);
    }

    float* op = out + (size_t)b*CIN*NN;
    #pragma unroll
    for (int oi = 0; oi < 4; ++oi) {
        int o = ob + oi*16 + lr;
        float sc = scale_l[o], sh = shift_l[o];
        #pragma unroll
        for (int ni = 0; ni < 4; ++ni) {
            int nbase = nb + ni*16 + lg*4;
            float4 st;
            float* sp_ = &st.x;
            #pragma unroll
            for (int j = 0; j < 4; ++j) {
                int n = nbase + j;
                sp_[j] = acc[ni][oi][j]*sc + sh + bf2f(Xs[(n*256 + o) ^ ((n&7)<<3)]);
            }
            *(float4*)(op + (size_t)o*NN + n0 + nbase) = st;
        }
    }
}

extern "C" void kernel_launch(void* const* d_in, const int* in_sizes, int n_in,
                              void* d_out, int out_size, void* d_ws, size_t ws_size,
                              hipStream_t stream)
{
    (void)in_sizes; (void)n_in; (void)out_size; (void)ws_size;
    const float* x     = (const float*)d_in[0];
    const float* gw    = (const float*)d_in[1];
    const float* gb    = (const float*)d_in[2];
    const float* tw    = (const float*)d_in[3];
    const float* tb    = (const float*)d_in[4];
    const float* pw    = (const float*)d_in[5];
    const float* pb    = (const float*)d_in[6];
    const float* Ww    = (const float*)d_in[7];
    const float* Wb    = (const float*)d_in[8];
    const float* gamma = (const float*)d_in[9];
    const float* beta  = (const float*)d_in[10];
    float* out = (float*)d_out;

    char* ws = (char*)d_ws;
    unsigned short* Sp  = (unsigned short*)(ws + 0);          // 16 MB
    float* Rp           = (float*)(ws + 16777216);            // 128 KB
    unsigned short* Sbf = (unsigned short*)(ws + 16908288);   // 1 MB
    float* rv           = (float*)(ws + 17956864);            // 8 KB
    unsigned short* Abf = (unsigned short*)(ws + 17965056);   // 128 KB
    unsigned short* CmT = (unsigned short*)(ws + 18096128);   // 128 KB
    unsigned short* Ebf = (unsigned short*)(ws + 18227200);   // 1 MB
    float* fv           = (float*)(ws + 19275776);            // 8 KB
    float* a1           = (float*)(ws + 19283968);            // 1 KB
    float* c1v          = (float*)(ws + 19284992);            // 1 KB
    float* p2           = (float*)(ws + 19286016);            // 1 KB
    float* params       = (float*)(ws + 19287040);            // 64 B
    float* stats        = (float*)(ws + 19287104);            // 2 KB

    kA <<<128, 512, 0, stream>>>(x, Sp, Rp);
    kRP<<<138, 512, 0, stream>>>(Sp, Rp, Ww, gw, tw, pw, gb, pb, tb,
                                 Sbf, rv, Abf, CmT, a1, c1v, p2, params, stats);
    kE <<<32,  512, 0, stream>>>(Sbf, rv, Abf, CmT, a1, c1v, p2, params, Wb, Ebf, fv, stats);
    kF <<<256, 512, 0, stream>>>(x, Ebf, fv, stats, gamma, beta, out);
}

// Round 7
// 90.045 us; speedup vs baseline: 2.2558x; 1.1193x over previous
//
#include <hip/hip_runtime.h>
#include <hip/hip_bf16.h>
#include <stdint.h>

#define BB   8
#define CIN  256
#define COUT 128
#define NN   4096

using f32x4  = __attribute__((ext_vector_type(4))) float;
using bf16x8 = __attribute__((ext_vector_type(8))) __bf16;
using u16x8  = __attribute__((ext_vector_type(8))) unsigned short;

static __device__ __forceinline__ unsigned short f2bf(float f) {
    unsigned int u = __builtin_bit_cast(unsigned int, f);
    u += 0x7FFFu + ((u >> 16) & 1u);
    return (unsigned short)(u >> 16);
}
static __device__ __forceinline__ float bf2f(unsigned short u) {
    return __builtin_bit_cast(float, (unsigned int)u << 16);
}
static __device__ __forceinline__ ushort4 pack4(float a, float b, float c, float d) {
    ushort4 r; r.x=f2bf(a); r.y=f2bf(b); r.z=f2bf(c); r.w=f2bf(d); return r;
}
#define MFMA(a,b,c) __builtin_amdgcn_mfma_f32_16x16x32_bf16((a),(b),(c),0,0,0)

static __device__ __forceinline__ int sw256(int r, int c) { return (r*256 + c) ^ ((r&7)<<3); }
static __device__ __forceinline__ int sw128(int r, int c) { return (r*128 + c) ^ ((r&7)<<3); }

// ============ kA: 130 blocks.
//   0-127: Gram partials Sp[bid] (bf16, LDS-restaged coalesced store) + Rp
//   128  : Abf = Ww*Gw, a1 = Ww*gb, zero stats
//   129  : CmT = Tw^T*Pw, c1v = Tw^T*pb, p2 = Pw^T*tb, sigma ============
__global__ __launch_bounds__(512) void kA(
    const float* __restrict__ x,
    const float* __restrict__ Wwf, const float* __restrict__ gwf,
    const float* __restrict__ twf, const float* __restrict__ pwf,
    const float* __restrict__ gbv, const float* __restrict__ pbv, const float* __restrict__ tbv,
    unsigned short* __restrict__ Sp, float* __restrict__ Rp,
    unsigned short* __restrict__ Abf, unsigned short* __restrict__ CmT,
    float* __restrict__ a1, float* __restrict__ c1v, float* __restrict__ p2,
    float* __restrict__ params, float* __restrict__ stats)
{
    __shared__ __align__(16) unsigned short SH[65536];   // 128 KB
    int bid = blockIdx.x;
    int t = threadIdx.x, lane = t & 63, wv = t >> 6;
    int lr = lane & 15, lg = lane >> 4;

    if (bid < 128) {
        int b = bid >> 4, ch = bid & 15;
        int n0 = ch * 256;
        const float* xb = x + (size_t)b*CIN*NN + n0;
        #pragma unroll
        for (int i = 0; i < 32; ++i) {
            int c = wv*32 + i;
            float4 f = *(const float4*)(xb + (size_t)c*NN + lane*4);
            float s = f.x + f.y + f.z + f.w;
            #pragma unroll
            for (int off = 1; off < 64; off <<= 1) s += __shfl_xor(s, off);
            if (lane == 0) Rp[bid*256 + c] = s;
            *(ushort4*)&SH[sw256(c, lane*4)] = pack4(f.x, f.y, f.z, f.w);
        }
        __syncthreads();

        int wr = wv >> 1, wc = wv & 1;      // 4x2: tile 64 x 128
        f32x4 acc[4][8];
        #pragma unroll
        for (int i = 0; i < 4; ++i)
            #pragma unroll
            for (int j = 0; j < 8; ++j) acc[i][j] = (f32x4){0.f,0.f,0.f,0.f};
        #pragma unroll
        for (int ks = 0; ks < 8; ++ks) {
            bf16x8 af[4], bfr[8];
            #pragma unroll
            for (int mi = 0; mi < 4; ++mi) {
                int row = wr*64 + mi*16 + lr;
                af[mi] = __builtin_bit_cast(bf16x8, *(const u16x8*)&SH[sw256(row, ks*32 + lg*8)]);
            }
            #pragma unroll
            for (int ni = 0; ni < 8; ++ni) {
                int row = wc*128 + ni*16 + lr;
                bfr[ni] = __builtin_bit_cast(bf16x8, *(const u16x8*)&SH[sw256(row, ks*32 + lg*8)]);
            }
            #pragma unroll
            for (int mi = 0; mi < 4; ++mi)
                #pragma unroll
                for (int ni = 0; ni < 8; ++ni)
                    acc[mi][ni] = MFMA(af[mi], bfr[ni], acc[mi][ni]);
        }
        __syncthreads();   // all SH reads complete before overwrite
        // dump acc -> SH (swizzled; 2-way conflicts only)
        #pragma unroll
        for (int mi = 0; mi < 4; ++mi)
            #pragma unroll
            for (int ni = 0; ni < 8; ++ni)
                #pragma unroll
                for (int j = 0; j < 4; ++j) {
                    int c1 = wr*64 + mi*16 + lg*4 + j;
                    int c2 = wc*128 + ni*16 + lr;
                    SH[sw256(c1, c2)] = f2bf(acc[mi][ni][j]);
                }
        __syncthreads();
        // coalesced u16x8 store: 512B contiguous per row
        unsigned short* dst = Sp + (size_t)bid * 65536;
        #pragma unroll
        for (int i = t; i < 8192; i += 512) {
            int row = i >> 5, q = i & 31;
            *(u16x8*)(dst + row*256 + ((q ^ (row&7)) * 8)) = *(const u16x8*)&SH[row*256 + q*8];
        }
        return;
    }

    // ---- weight precompute blocks ----
    unsigned short* Ls = SH;
    unsigned short* Rs = SH + 32768;
    if (bid == 128) {
        for (int i = t; i < 8192; i += 512) {
            int flat = i*4, r = flat >> 7, c = flat & 127;
            float4 f = *(const float4*)(Wwf + flat);
            *(ushort4*)&Ls[sw128(r, c)] = pack4(f.x, f.y, f.z, f.w);
        }
        {
            int c = lane * 4;  int k4 = wv * 4;
            #pragma unroll
            for (int rep = 0; rep < 4; ++rep) {
                int kb = rep*32 + k4;
                float4 f0 = *(const float4*)(gwf + (size_t)(kb+0)*256 + c);
                float4 f1 = *(const float4*)(gwf + (size_t)(kb+1)*256 + c);
                float4 f2 = *(const float4*)(gwf + (size_t)(kb+2)*256 + c);
                float4 f3 = *(const float4*)(gwf + (size_t)(kb+3)*256 + c);
                *(ushort4*)&Rs[sw128(c+0, kb)] = pack4(f0.x, f1.x, f2.x, f3.x);
                *(ushort4*)&Rs[sw128(c+1, kb)] = pack4(f0.y, f1.y, f2.y, f3.y);
                *(ushort4*)&Rs[sw128(c+2, kb)] = pack4(f0.z, f1.z, f2.z, f3.z);
                *(ushort4*)&Rs[sw128(c+3, kb)] = pack4(f0.w, f1.w, f2.w, f3.w);
            }
        }
        if (t < 512) stats[t] = 0.f;
    } else {
        {
            int c = lane * 4;  int k4 = wv * 4;
            #pragma unroll
            for (int rep = 0; rep < 4; ++rep) {
                int kb = rep*32 + k4;
                float4 f0 = *(const float4*)(twf + (size_t)(kb+0)*256 + c);
                float4 f1 = *(const float4*)(twf + (size_t)(kb+1)*256 + c);
                float4 f2 = *(const float4*)(twf + (size_t)(kb+2)*256 + c);
                float4 f3 = *(const float4*)(twf + (size_t)(kb+3)*256 + c);
                *(ushort4*)&Ls[sw128(c+0, kb)] = pack4(f0.x, f1.x, f2.x, f3.x);
                *(ushort4*)&Ls[sw128(c+1, kb)] = pack4(f0.y, f1.y, f2.y, f3.y);
                *(ushort4*)&Ls[sw128(c+2, kb)] = pack4(f0.z, f1.z, f2.z, f3.z);
                *(ushort4*)&Ls[sw128(c+3, kb)] = pack4(f0.w, f1.w, f2.w, f3.w);
                float4 g0 = *(const float4*)(pwf + (size_t)(kb+0)*256 + c);
                float4 g1 = *(const float4*)(pwf + (size_t)(kb+1)*256 + c);
                float4 g2 = *(const float4*)(pwf + (size_t)(kb+2)*256 + c);
                float4 g3 = *(const float4*)(pwf + (size_t)(kb+3)*256 + c);
                *(ushort4*)&Rs[sw128(c+0, kb)] = pack4(g0.x, g1.x, g2.x, g3.x);
                *(ushort4*)&Rs[sw128(c+1, kb)] = pack4(g0.y, g1.y, g2.y, g3.y);
                *(ushort4*)&Rs[sw128(c+2, kb)] = pack4(g0.z, g1.z, g2.z, g3.z);
                *(ushort4*)&Rs[sw128(c+3, kb)] = pack4(g0.w, g1.w, g2.w, g3.w);
            }
        }
    }
    __syncthreads();

    int wr = wv >> 2, wc = wv & 3;      // 2x4: tile 128 x 64
    f32x4 acc[8][4];
    #pragma unroll
    for (int i = 0; i < 8; ++i)
        #pragma unroll
        for (int j = 0; j < 4; ++j) acc[i][j] = (f32x4){0.f,0.f,0.f,0.f};
    #pragma unroll
    for (int ks = 0; ks < 4; ++ks) {
        bf16x8 af[8], bfr[4];
        #pragma unroll
        for (int mi = 0; mi < 8; ++mi) {
            int r = wr*128 + mi*16 + lr;
            af[mi] = __builtin_bit_cast(bf16x8, *(const u16x8*)&Ls[sw128(r, ks*32 + lg*8)]);
        }
        #pragma unroll
        for (int ni = 0; ni < 4; ++ni) {
            int c = wc*64 + ni*16 + lr;
            bfr[ni] = __builtin_bit_cast(bf16x8, *(const u16x8*)&Rs[sw128(c, ks*32 + lg*8)]);
        }
        #pragma unroll
        for (int mi = 0; mi < 8; ++mi)
            #pragma unroll
            for (int ni = 0; ni < 4; ++ni)
                acc[mi][ni] = MFMA(af[mi], bfr[ni], acc[mi][ni]);
    }
    unsigned short* Dst = (bid == 128) ? Abf : CmT;
    #pragma unroll
    for (int mi = 0; mi < 8; ++mi)
        #pragma unroll
        for (int ni = 0; ni < 4; ++ni)
            #pragma unroll
            for (int j = 0; j < 4; ++j) {
                int r = wr*128 + mi*16 + lg*4 + j;
                int c = wc*64 + ni*16 + lr;
                Dst[r*256 + c] = f2bf(acc[mi][ni][j]);
            }

    if (bid == 128) {
        if (t < 256) {
            float s = 0.f;
            #pragma unroll
            for (int q = 0; q < 32; ++q) {
                float4 f = *(const float4*)(Wwf + (size_t)t*128 + q*4);
                s += f.x*gbv[q*4] + f.y*gbv[q*4+1] + f.z*gbv[q*4+2] + f.w*gbv[q*4+3];
            }
            a1[t] = s;
        }
    } else {
        if (t < 256) {
            float s1 = 0.f, s2 = 0.f;
            for (int k = 0; k < 128; ++k) {
                s1 += twf[(size_t)k*256 + t] * pbv[k];
                s2 += pwf[(size_t)k*256 + t] * tbv[k];
            }
            c1v[t] = s1; p2[t] = s2;
        }
        if (t < 64) {
            float v = pbv[t]*tbv[t] + pbv[t+64]*tbv[t+64];
            #pragma unroll
            for (int off = 1; off < 64; off <<= 1) v += __shfl_xor(v, off);
            if (t == 0) params[0] = v;
        }
    }
}

// ============ kR: 136 blocks. 0-127: Sbf[b] = sum 16 partials; 128-135: rv ============
__global__ __launch_bounds__(512) void kR(
    const unsigned short* __restrict__ Sp, const float* __restrict__ Rp,
    unsigned short* __restrict__ Sbf, float* __restrict__ rv)
{
    int bid = blockIdx.x, t = threadIdx.x;
    if (bid < 128) {
        int b = bid >> 4, sl = bid & 15;
        int base = sl*4096 + t*8;
        float s[8] = {0.f,0.f,0.f,0.f,0.f,0.f,0.f,0.f};
        #pragma unroll
        for (int i = 0; i < 16; ++i) {
            u16x8 v = *(const u16x8*)(Sp + (size_t)(b*16 + i)*65536 + base);
            #pragma unroll
            for (int e = 0; e < 8; ++e) s[e] += bf2f(v[e]);
        }
        u16x8 o;
        #pragma unroll
        for (int e = 0; e < 8; ++e) o[e] = f2bf(s[e]);
        *(u16x8*)(Sbf + (size_t)b*65536 + base) = o;
    } else {
        int b = bid - 128;
        if (t < 256) {
            float s = 0.f;
            #pragma unroll
            for (int i = 0; i < 16; ++i) s += Rp[(b*16 + i)*256 + t];
            rv[b*256 + t] = s;
        }
    }
}

// ============ kE: 32 blocks (b, o-slice of 64). Y=A_sl*S; E=(Y*Cm)/N + rank-2; f; BN stats ============
__global__ __launch_bounds__(512) void kE(
    const unsigned short* __restrict__ Sbf, const float* __restrict__ rv,
    const unsigned short* __restrict__ Abf, const unsigned short* __restrict__ CmT,
    const float* __restrict__ a1g, const float* __restrict__ c1vg, const float* __restrict__ p2g,
    const float* __restrict__ params, const float* __restrict__ Wbv,
    unsigned short* __restrict__ Ebf, float* __restrict__ fv, float* __restrict__ stats)
{
    __shared__ __align__(16) unsigned short Ybuf[16384];  // [64][256] swz
    __shared__ __align__(16) unsigned short Ebuf[16384];  // [64][256] swz
    __shared__ float r_l[256], p2_l[256], c1v_l[256], cr[256];
    __shared__ float a1_l[64], ar[64], Yp2[64], er[64], diag_l[64];
    __shared__ float rp2_s;
    int blk = blockIdx.x;
    int b = blk >> 2, obase = (blk & 3) * 64;
    int t = threadIdx.x, lane = t & 63, wv = t >> 6;
    int lr = lane & 15, lg = lane >> 4;
    const float invN = 1.0f/4096.0f;
    const unsigned short* Sb = Sbf + (size_t)b*65536;

    if (t < 256) {
        r_l[t] = rv[b*256 + t];
        p2_l[t] = p2g[t];
        c1v_l[t] = c1vg[t];
    } else if (t < 320) {
        a1_l[t - 256] = a1g[obase + (t - 256)];
    }
    __syncthreads();

    // GEMM1: Y[64][256] = A_sl * S
    f32x4 acc[4][2];
    #pragma unroll
    for (int i = 0; i < 4; ++i) { acc[i][0] = (f32x4){0,0,0,0}; acc[i][1] = (f32x4){0,0,0,0}; }
    const unsigned short* Arow0 = Abf + (size_t)obase*256;
    #pragma unroll
    for (int ks = 0; ks < 8; ++ks) {
        bf16x8 a4[4], b2[2];
        #pragma unroll
        for (int mi = 0; mi < 4; ++mi)
            a4[mi] = __builtin_bit_cast(bf16x8, *(const u16x8*)(Arow0 + (size_t)(mi*16+lr)*256 + ks*32 + lg*8));
        #pragma unroll
        for (int ni = 0; ni < 2; ++ni)
            b2[ni] = __builtin_bit_cast(bf16x8, *(const u16x8*)(Sb + (size_t)(wv*32+ni*16+lr)*256 + ks*32 + lg*8));
        #pragma unroll
        for (int mi = 0; mi < 4; ++mi)
            #pragma unroll
            for (int ni = 0; ni < 2; ++ni)
                acc[mi][ni] = MFMA(a4[mi], b2[ni], acc[mi][ni]);
    }
    #pragma unroll
    for (int mi = 0; mi < 4; ++mi)
        #pragma unroll
        for (int ni = 0; ni < 2; ++ni)
            #pragma unroll
            for (int j = 0; j < 4; ++j) {
                int ol = mi*16 + lg*4 + j;
                int c2 = wv*32 + ni*16 + lr;
                Ybuf[ol*256 + (c2 ^ ((ol&7)<<3))] = f2bf(acc[mi][ni][j]);
            }
    __syncthreads();

    {
        int row = t >> 3, p8 = t & 7;
        float sA = 0.f, sY = 0.f;
        const unsigned short* Ar = Abf + (size_t)(obase + row)*256 + p8*32;
        #pragma unroll
        for (int q = 0; q < 4; ++q) {
            u16x8 av = *(const u16x8*)(Ar + q*8);
            #pragma unroll
            for (int e = 0; e < 8; ++e) {
                int c = p8*32 + q*8 + e;
                sA += bf2f(av[e]) * r_l[c];
                sY += bf2f(Ybuf[row*256 + (c ^ ((row&7)<<3))]) * p2_l[c];
            }
        }
        sA += __shfl_xor(sA, 1); sA += __shfl_xor(sA, 2); sA += __shfl_xor(sA, 4);
        sY += __shfl_xor(sY, 1); sY += __shfl_xor(sY, 2); sY += __shfl_xor(sY, 4);
        if (p8 == 0) { ar[row] = sA; Yp2[row] = sY; }
    }
    if (t < 256) {
        float s = 0.f;
        const unsigned short* Cr = CmT + (size_t)t*256;
        #pragma unroll
        for (int q = 0; q < 32; ++q) {
            u16x8 v = *(const u16x8*)(Cr + q*8);
            #pragma unroll
            for (int e = 0; e < 8; ++e) s += bf2f(v[e]) * r_l[q*8 + e];
        }
        cr[t] = s;
    }
    if (t < 64) {
        float v = r_l[t*4]*p2_l[t*4] + r_l[t*4+1]*p2_l[t*4+1]
                + r_l[t*4+2]*p2_l[t*4+2] + r_l[t*4+3]*p2_l[t*4+3];
        #pragma unroll
        for (int off = 1; off < 64; off <<= 1) v += __shfl_xor(v, off);
        if (t == 0) rp2_s = v;
    }
    __syncthreads();

    // GEMM2: E = (Y*Cm)/N + a1*cr^T/N + (ar/N + a1)*c1v^T
    f32x4 accE[4][2];
    #pragma unroll
    for (int i = 0; i < 4; ++i) { accE[i][0] = (f32x4){0,0,0,0}; accE[i][1] = (f32x4){0,0,0,0}; }
    #pragma unroll
    for (int ks = 0; ks < 8; ++ks) {
        bf16x8 a4[4], b2[2];
        #pragma unroll
        for (int mi = 0; mi < 4; ++mi) {
            int ol = mi*16 + lr;
            a4[mi] = __builtin_bit_cast(bf16x8, *(const u16x8*)&Ybuf[ol*256 + ((ks*32 + lg*8) ^ ((ol&7)<<3))]);
        }
        #pragma unroll
        for (int ni = 0; ni < 2; ++ni)
            b2[ni] = __builtin_bit_cast(bf16x8, *(const u16x8*)(CmT + (size_t)(wv*32+ni*16+lr)*256 + ks*32 + lg*8));
        #pragma unroll
        for (int mi = 0; mi < 4; ++mi)
            #pragma unroll
            for (int ni = 0; ni < 2; ++ni)
                accE[mi][ni] = MFMA(a4[mi], b2[ni], accE[mi][ni]);
    }
    unsigned short* Eb = Ebf + (size_t)b*65536;
    #pragma unroll
    for (int mi = 0; mi < 4; ++mi)
        #pragma unroll
        for (int ni = 0; ni < 2; ++ni)
            #pragma unroll
            for (int j = 0; j < 4; ++j) {
                int ol = mi*16 + lg*4 + j;
                int cp = wv*32 + ni*16 + lr;
                float e = accE[mi][ni][j]*invN + a1_l[ol]*invN*cr[cp]
                        + (invN*ar[ol] + a1_l[ol])*c1v_l[cp];
                unsigned short eb = f2bf(e);
                Ebuf[ol*256 + (cp ^ ((ol&7)<<3))] = eb;
                Eb[(size_t)(obase + ol)*256 + cp] = eb;
            }
    __syncthreads();

    float f_reg = 0.f;
    {
        int row = t >> 3, p8 = t & 7;
        float s = 0.f;
        #pragma unroll
        for (int q = 0; q < 4; ++q)
            #pragma unroll
            for (int e = 0; e < 8; ++e) {
                int c = p8*32 + q*8 + e;
                s += bf2f(Ebuf[row*256 + (c ^ ((row&7)<<3))]) * r_l[c];
            }
        s += __shfl_xor(s, 1); s += __shfl_xor(s, 2); s += __shfl_xor(s, 4);
        if (p8 == 0) er[row] = s;
    }
    if (t < 64) {
        diag_l[t] = 0.f;
        float sg = params[0];
        f_reg = invN*(Yp2[t] + a1_l[t]*rp2_s + ar[t]*sg) + a1_l[t]*sg + Wbv[obase + t];
        fv[b*256 + obase + t] = f_reg;
    }
    __syncthreads();

    // GEMM3: Z = E_sl * S ; diag[o] = sum_c2 Z[o][c2]*E[o][c2]
    f32x4 accZ[4][2];
    #pragma unroll
    for (int i = 0; i < 4; ++i) { accZ[i][0] = (f32x4){0,0,0,0}; accZ[i][1] = (f32x4){0,0,0,0}; }
    #pragma unroll
    for (int ks = 0; ks < 8; ++ks) {
        bf16x8 a4[4], b2[2];
        #pragma unroll
        for (int mi = 0; mi < 4; ++mi) {
            int ol = mi*16 + lr;
            a4[mi] = __builtin_bit_cast(bf16x8, *(const u16x8*)&Ebuf[ol*256 + ((ks*32 + lg*8) ^ ((ol&7)<<3))]);
        }
        #pragma unroll
        for (int ni = 0; ni < 2; ++ni)
            b2[ni] = __builtin_bit_cast(bf16x8, *(const u16x8*)(Sb + (size_t)(wv*32+ni*16+lr)*256 + ks*32 + lg*8));
        #pragma unroll
        for (int mi = 0; mi < 4; ++mi)
            #pragma unroll
            for (int ni = 0; ni < 2; ++ni)
                accZ[mi][ni] = MFMA(a4[mi], b2[ni], accZ[mi][ni]);
    }
    #pragma unroll
    for (int mi = 0; mi < 4; ++mi)
        #pragma unroll
        for (int j = 0; j < 4; ++j) {
            int ol = mi*16 + lg*4 + j;
            float s = 0.f;
            #pragma unroll
            for (int ni = 0; ni < 2; ++ni) {
                int c2 = wv*32 + ni*16 + lr;
                s += accZ[mi][ni][j] * bf2f(Ebuf[ol*256 + (c2 ^ ((ol&7)<<3))]);
            }
            s += __shfl_xor(s, 1); s += __shfl_xor(s, 2);
            s += __shfl_xor(s, 4); s += __shfl_xor(s, 8);
            if (lr == 0) atomicAdd(&diag_l[ol], s);
        }
    __syncthreads();

    if (t < 64) {
        int o = obase + t;
        atomicAdd(&stats[o], er[t] + 4096.0f*f_reg);
        atomicAdd(&stats[256 + o], diag_l[t] + 2.0f*f_reg*er[t] + 4096.0f*f_reg*f_reg);
    }
}

// ============ kF: out = (E x + f - mu)*gamma*rsqrt(var+eps) + beta + x  (coalesced 64B-segment stores) ====
__global__ __launch_bounds__(512) void kF(
    const float* __restrict__ x, const unsigned short* __restrict__ Ebf,
    const float* __restrict__ fv, const float* __restrict__ stats,
    const float* __restrict__ gamma, const float* __restrict__ beta,
    float* __restrict__ out)
{
    __shared__ __align__(16) unsigned short Xs[128*256];  // 64 KB, [n][c] swz
    __shared__ float scale_l[256], shift_l[256];
    int b = blockIdx.x >> 5, n0 = (blockIdx.x & 31) * 128;
    int t = threadIdx.x, lane = t & 63, wv = t >> 6, lr = lane & 15, lg = lane >> 4;
    const float inv = 1.0f / 32768.0f;
    if (t < 256) {
        float mu  = stats[t] * inv;
        float var = stats[256 + t] * inv - mu*mu;
        float sc  = gamma[t] * rsqrtf(var + 1e-5f);
        scale_l[t] = sc;
        shift_l[t] = (fv[b*256 + t] - mu) * sc + beta[t];
    }
    {
        int nq = (t & 31) * 4, c0 = (t >> 5) * 4;
        const float* xb = x + (size_t)b*CIN*NN + n0 + nq;
        #pragma unroll
        for (int p = 0; p < 4; ++p) {
            int c = p*64 + c0;
            const float* xp = xb + (size_t)c*NN;
            float4 f0 = *(const float4*)(xp);
            float4 f1 = *(const float4*)(xp + NN);
            float4 f2 = *(const float4*)(xp + 2*NN);
            float4 f3 = *(const float4*)(xp + 3*NN);
            *(ushort4*)&Xs[(nq+0)*256 + (c ^ (((nq+0)&7)<<3))] = pack4(f0.x,f1.x,f2.x,f3.x);
            *(ushort4*)&Xs[(nq+1)*256 + (c ^ (((nq+1)&7)<<3))] = pack4(f0.y,f1.y,f2.y,f3.y);
            *(ushort4*)&Xs[(nq+2)*256 + (c ^ (((nq+2)&7)<<3))] = pack4(f0.z,f1.z,f2.z,f3.z);
            *(ushort4*)&Xs[(nq+3)*256 + (c ^ (((nq+3)&7)<<3))] = pack4(f0.w,f1.w,f2.w,f3.w);
        }
    }
    __syncthreads();

    int wn = wv >> 2, wo = wv & 3;
    int nb = wn*64, ob = wo*64;
    const unsigned short* Eb = Ebf + (size_t)b*65536;
    f32x4 acc[4][4];   // [oi][ni]
    #pragma unroll
    for (int i = 0; i < 4; ++i)
        #pragma unroll
        for (int j = 0; j < 4; ++j) acc[i][j] = (f32x4){0,0,0,0};

    #pragma unroll
    for (int ks = 0; ks < 8; ++ks) {
        bf16x8 xf[4], ef[4];
        #pragma unroll
        for (int ni = 0; ni < 4; ++ni) {
            int n = nb + ni*16 + lr;
            xf[ni] = __builtin_bit_cast(bf16x8, *(const u16x8*)&Xs[(n*256 + ks*32 + lg*8) ^ ((n&7)<<3)]);
        }
        #pragma unroll
        for (int oi = 0; oi < 4; ++oi) {
            int o = ob + oi*16 + lr;
            ef[oi] = __builtin_bit_cast(bf16x8, *(const u16x8*)(Eb + (size_t)o*256 + ks*32 + lg*8));
        }
        // swapped operand order: D[o][n], col(lr)=n -> coalesced stores along n
        #pragma unroll
        for (int oi = 0; oi < 4; ++oi)
            #pragma unroll
            for (int ni = 0; ni < 4; ++ni)
                acc[oi][ni] = MFMA(ef[oi], xf[ni], acc[oi][ni]);
    }

    float* op = out + (size_t)b*CIN*NN + n0;
    #pragma unroll
    for (int oi = 0; oi < 4; ++oi) {
        #pragma unroll
        for (int j = 0; j < 4; ++j) {
            int o = ob + oi*16 + lg*4 + j;
            float sc = scale_l[o], sh = shift_l[o];
            #pragma unroll
            for (int ni = 0; ni < 4; ++ni) {
                int n = nb + ni*16 + lr;
                float val = acc[oi][ni][j]*sc + sh + bf2f(Xs[(n*256 + (o ^ ((n&7)<<3)))]);
                op[(size_t)o*NN + n] = val;
            }
        }
    }
}

extern "C" void kernel_launch(void* const* d_in, const int* in_sizes, int n_in,
                              void* d_out, int out_size, void* d_ws, size_t ws_size,
                              hipStream_t stream)
{
    (void)in_sizes; (void)n_in; (void)out_size; (void)ws_size;
    const float* x     = (const float*)d_in[0];
    const float* gw    = (const float*)d_in[1];
    const float* gb    = (const float*)d_in[2];
    const float* tw    = (const float*)d_in[3];
    const float* tb    = (const float*)d_in[4];
    const float* pw    = (const float*)d_in[5];
    const float* pb    = (const float*)d_in[6];
    const float* Ww    = (const float*)d_in[7];
    const float* Wb    = (const float*)d_in[8];
    const float* gamma = (const float*)d_in[9];
    const float* beta  = (const float*)d_in[10];
    float* out = (float*)d_out;

    char* ws = (char*)d_ws;
    unsigned short* Sp  = (unsigned short*)(ws + 0);          // 16 MB
    float* Rp           = (float*)(ws + 16777216);            // 128 KB
    unsigned short* Sbf = (unsigned short*)(ws + 16908288);   // 1 MB
    float* rv           = (float*)(ws + 17956864);            // 8 KB
    unsigned short* Abf = (unsigned short*)(ws + 17965056);   // 128 KB
    unsigned short* CmT = (unsigned short*)(ws + 18096128);   // 128 KB
    unsigned short* Ebf = (unsigned short*)(ws + 18227200);   // 1 MB
    float* fv           = (float*)(ws + 19275776);            // 8 KB
    float* a1           = (float*)(ws + 19283968);            // 1 KB
    float* c1v          = (float*)(ws + 19284992);            // 1 KB
    float* p2           = (float*)(ws + 19286016);            // 1 KB
    float* params       = (float*)(ws + 19287040);            // 64 B
    float* stats        = (float*)(ws + 19287104);            // 2 KB

    kA<<<130, 512, 0, stream>>>(x, Ww, gw, tw, pw, gb, pb, tb,
                                Sp, Rp, Abf, CmT, a1, c1v, p2, params, stats);
    kR<<<136, 512, 0, stream>>>(Sp, Rp, Sbf, rv);
    kE<<<32,  512, 0, stream>>>(Sbf, rv, Abf, CmT, a1, c1v, p2, params, Wb, Ebf, fv, stats);
    kF<<<256, 512, 0, stream>>>(x, Ebf, fv, stats, gamma, beta, out);
}

// Round 8
// 83.208 us; speedup vs baseline: 2.4412x; 1.0822x over previous
//
#include <hip/hip_runtime.h>
#include <hip/hip_bf16.h>
#include <stdint.h>

#define BB   8
#define CIN  256
#define COUT 128
#define NN   4096

using f32x4  = __attribute__((ext_vector_type(4))) float;
using bf16x8 = __attribute__((ext_vector_type(8))) __bf16;
using u16x8  = __attribute__((ext_vector_type(8))) unsigned short;

static __device__ __forceinline__ unsigned short f2bf(float f) {
    unsigned int u = __builtin_bit_cast(unsigned int, f);
    u += 0x7FFFu + ((u >> 16) & 1u);
    return (unsigned short)(u >> 16);
}
static __device__ __forceinline__ float bf2f(unsigned short u) {
    return __builtin_bit_cast(float, (unsigned int)u << 16);
}
static __device__ __forceinline__ ushort4 pack4(float a, float b, float c, float d) {
    ushort4 r; r.x=f2bf(a); r.y=f2bf(b); r.z=f2bf(c); r.w=f2bf(d); return r;
}
#define MFMA(a,b,c) __builtin_amdgcn_mfma_f32_16x16x32_bf16((a),(b),(c),0,0,0)

static __device__ __forceinline__ int sw256(int r, int c) { return (r*256 + c) ^ ((r&7)<<3); }
static __device__ __forceinline__ int sw128(int r, int c) { return (r*128 + c) ^ ((r&7)<<3); }

// ============ kA: 130 blocks.
//   0-127: Gram partials Sp[bid] (bf16) + Rp (row-sums from LDS, off load path)
//   128  : Abf = Ww*Gw, a1 = Ww*gb, zero stats
//   129  : CmT = Tw^T*Pw, c1v = Tw^T*pb, p2 = Pw^T*tb, sigma ============
__global__ __launch_bounds__(512) void kA(
    const float* __restrict__ x,
    const float* __restrict__ Wwf, const float* __restrict__ gwf,
    const float* __restrict__ twf, const float* __restrict__ pwf,
    const float* __restrict__ gbv, const float* __restrict__ pbv, const float* __restrict__ tbv,
    unsigned short* __restrict__ Sp, float* __restrict__ Rp,
    unsigned short* __restrict__ Abf, unsigned short* __restrict__ CmT,
    float* __restrict__ a1, float* __restrict__ c1v, float* __restrict__ p2,
    float* __restrict__ params, float* __restrict__ stats)
{
    __shared__ __align__(16) unsigned short SH[65536];   // 128 KB
    int bid = blockIdx.x;
    int t = threadIdx.x, lane = t & 63, wv = t >> 6;
    int lr = lane & 15, lg = lane >> 4;

    if (bid < 128) {
        int b = bid >> 4, ch = bid & 15;
        int n0 = ch * 256;
        const float* xb = x + (size_t)b*CIN*NN + n0 + lane*4;
        // two-phase staging: 16 loads in flight, then convert+write
        #pragma unroll
        for (int g = 0; g < 2; ++g) {
            float4 v[16];
            #pragma unroll
            for (int i = 0; i < 16; ++i) {
                int c = wv*32 + g*16 + i;
                v[i] = *(const float4*)(xb + (size_t)c*NN);
            }
            #pragma unroll
            for (int i = 0; i < 16; ++i) {
                int c = wv*32 + g*16 + i;
                *(ushort4*)&SH[sw256(c, lane*4)] = pack4(v[i].x, v[i].y, v[i].z, v[i].w);
            }
        }
        __syncthreads();

        int wr = wv >> 1, wc = wv & 1;      // 4x2: tile 64 x 128
        f32x4 acc[4][8];
        #pragma unroll
        for (int i = 0; i < 4; ++i)
            #pragma unroll
            for (int j = 0; j < 8; ++j) acc[i][j] = (f32x4){0.f,0.f,0.f,0.f};
        #pragma unroll
        for (int ks = 0; ks < 8; ++ks) {
            bf16x8 af[4], bfr[8];
            #pragma unroll
            for (int mi = 0; mi < 4; ++mi) {
                int row = wr*64 + mi*16 + lr;
                af[mi] = __builtin_bit_cast(bf16x8, *(const u16x8*)&SH[sw256(row, ks*32 + lg*8)]);
            }
            #pragma unroll
            for (int ni = 0; ni < 8; ++ni) {
                int row = wc*128 + ni*16 + lr;
                bfr[ni] = __builtin_bit_cast(bf16x8, *(const u16x8*)&SH[sw256(row, ks*32 + lg*8)]);
            }
            #pragma unroll
            for (int mi = 0; mi < 4; ++mi)
                #pragma unroll
                for (int ni = 0; ni < 8; ++ni)
                    acc[mi][ni] = MFMA(af[mi], bfr[ni], acc[mi][ni]);
        }
        // row-sums from LDS (off the load critical path)
        if (t < 256) {
            float s = 0.f;
            #pragma unroll
            for (int q = 0; q < 32; ++q) {
                u16x8 vv = *(const u16x8*)&SH[sw256(t, q*8)];
                #pragma unroll
                for (int e = 0; e < 8; ++e) s += bf2f(vv[e]);
            }
            Rp[bid*256 + t] = s;
        }
        __syncthreads();   // all SH reads complete before overwrite
        // dump acc -> SH (swizzled)
        #pragma unroll
        for (int mi = 0; mi < 4; ++mi)
            #pragma unroll
            for (int ni = 0; ni < 8; ++ni)
                #pragma unroll
                for (int j = 0; j < 4; ++j) {
                    int c1 = wr*64 + mi*16 + lg*4 + j;
                    int c2 = wc*128 + ni*16 + lr;
                    SH[sw256(c1, c2)] = f2bf(acc[mi][ni][j]);
                }
        __syncthreads();
        // coalesced u16x8 store: 512B contiguous per row
        unsigned short* dst = Sp + (size_t)bid * 65536;
        #pragma unroll
        for (int i = t; i < 8192; i += 512) {
            int row = i >> 5, q = i & 31;
            *(u16x8*)(dst + row*256 + ((q ^ (row&7)) * 8)) = *(const u16x8*)&SH[row*256 + q*8];
        }
        return;
    }

    // ---- weight precompute blocks ----
    unsigned short* Ls = SH;
    unsigned short* Rs = SH + 32768;
    if (bid == 128) {
        for (int i = t; i < 8192; i += 512) {
            int flat = i*4, r = flat >> 7, c = flat & 127;
            float4 f = *(const float4*)(Wwf + flat);
            *(ushort4*)&Ls[sw128(r, c)] = pack4(f.x, f.y, f.z, f.w);
        }
        {
            int c = lane * 4;  int k4 = wv * 4;
            #pragma unroll
            for (int rep = 0; rep < 4; ++rep) {
                int kb = rep*32 + k4;
                float4 f0 = *(const float4*)(gwf + (size_t)(kb+0)*256 + c);
                float4 f1 = *(const float4*)(gwf + (size_t)(kb+1)*256 + c);
                float4 f2 = *(const float4*)(gwf + (size_t)(kb+2)*256 + c);
                float4 f3 = *(const float4*)(gwf + (size_t)(kb+3)*256 + c);
                *(ushort4*)&Rs[sw128(c+0, kb)] = pack4(f0.x, f1.x, f2.x, f3.x);
                *(ushort4*)&Rs[sw128(c+1, kb)] = pack4(f0.y, f1.y, f2.y, f3.y);
                *(ushort4*)&Rs[sw128(c+2, kb)] = pack4(f0.z, f1.z, f2.z, f3.z);
                *(ushort4*)&Rs[sw128(c+3, kb)] = pack4(f0.w, f1.w, f2.w, f3.w);
            }
        }
        if (t < 512) stats[t] = 0.f;
    } else {
        {
            int c = lane * 4;  int k4 = wv * 4;
            #pragma unroll
            for (int rep = 0; rep < 4; ++rep) {
                int kb = rep*32 + k4;
                float4 f0 = *(const float4*)(twf + (size_t)(kb+0)*256 + c);
                float4 f1 = *(const float4*)(twf + (size_t)(kb+1)*256 + c);
                float4 f2 = *(const float4*)(twf + (size_t)(kb+2)*256 + c);
                float4 f3 = *(const float4*)(twf + (size_t)(kb+3)*256 + c);
                *(ushort4*)&Ls[sw128(c+0, kb)] = pack4(f0.x, f1.x, f2.x, f3.x);
                *(ushort4*)&Ls[sw128(c+1, kb)] = pack4(f0.y, f1.y, f2.y, f3.y);
                *(ushort4*)&Ls[sw128(c+2, kb)] = pack4(f0.z, f1.z, f2.z, f3.z);
                *(ushort4*)&Ls[sw128(c+3, kb)] = pack4(f0.w, f1.w, f2.w, f3.w);
                float4 g0 = *(const float4*)(pwf + (size_t)(kb+0)*256 + c);
                float4 g1 = *(const float4*)(pwf + (size_t)(kb+1)*256 + c);
                float4 g2 = *(const float4*)(pwf + (size_t)(kb+2)*256 + c);
                float4 g3 = *(const float4*)(pwf + (size_t)(kb+3)*256 + c);
                *(ushort4*)&Rs[sw128(c+0, kb)] = pack4(g0.x, g1.x, g2.x, g3.x);
                *(ushort4*)&Rs[sw128(c+1, kb)] = pack4(g0.y, g1.y, g2.y, g3.y);
                *(ushort4*)&Rs[sw128(c+2, kb)] = pack4(g0.z, g1.z, g2.z, g3.z);
                *(ushort4*)&Rs[sw128(c+3, kb)] = pack4(g0.w, g1.w, g2.w, g3.w);
            }
        }
    }
    __syncthreads();

    int wr = wv >> 2, wc = wv & 3;      // 2x4: tile 128 x 64
    f32x4 acc[8][4];
    #pragma unroll
    for (int i = 0; i < 8; ++i)
        #pragma unroll
        for (int j = 0; j < 4; ++j) acc[i][j] = (f32x4){0.f,0.f,0.f,0.f};
    #pragma unroll
    for (int ks = 0; ks < 4; ++ks) {
        bf16x8 af[8], bfr[4];
        #pragma unroll
        for (int mi = 0; mi < 8; ++mi) {
            int r = wr*128 + mi*16 + lr;
            af[mi] = __builtin_bit_cast(bf16x8, *(const u16x8*)&Ls[sw128(r, ks*32 + lg*8)]);
        }
        #pragma unroll
        for (int ni = 0; ni < 4; ++ni) {
            int c = wc*64 + ni*16 + lr;
            bfr[ni] = __builtin_bit_cast(bf16x8, *(const u16x8*)&Rs[sw128(c, ks*32 + lg*8)]);
        }
        #pragma unroll
        for (int mi = 0; mi < 8; ++mi)
            #pragma unroll
            for (int ni = 0; ni < 4; ++ni)
                acc[mi][ni] = MFMA(af[mi], bfr[ni], acc[mi][ni]);
    }
    unsigned short* Dst = (bid == 128) ? Abf : CmT;
    #pragma unroll
    for (int mi = 0; mi < 8; ++mi)
        #pragma unroll
        for (int ni = 0; ni < 4; ++ni)
            #pragma unroll
            for (int j = 0; j < 4; ++j) {
                int r = wr*128 + mi*16 + lg*4 + j;
                int c = wc*64 + ni*16 + lr;
                Dst[r*256 + c] = f2bf(acc[mi][ni][j]);
            }

    if (bid == 128) {
        if (t < 256) {
            float s = 0.f;
            #pragma unroll
            for (int q = 0; q < 32; ++q) {
                float4 f = *(const float4*)(Wwf + (size_t)t*128 + q*4);
                s += f.x*gbv[q*4] + f.y*gbv[q*4+1] + f.z*gbv[q*4+2] + f.w*gbv[q*4+3];
            }
            a1[t] = s;
        }
    } else {
        if (t < 256) {
            float s1 = 0.f, s2 = 0.f;
            for (int k = 0; k < 128; ++k) {
                s1 += twf[(size_t)k*256 + t] * pbv[k];
                s2 += pwf[(size_t)k*256 + t] * tbv[k];
            }
            c1v[t] = s1; p2[t] = s2;
        }
        if (t < 64) {
            float v = pbv[t]*tbv[t] + pbv[t+64]*tbv[t+64];
            #pragma unroll
            for (int off = 1; off < 64; off <<= 1) v += __shfl_xor(v, off);
            if (t == 0) params[0] = v;
        }
    }
}

// ============ kR: 136 blocks. 0-127: Sbf[b] = sum 16 partials; 128-135: rv ============
__global__ __launch_bounds__(512) void kR(
    const unsigned short* __restrict__ Sp, const float* __restrict__ Rp,
    unsigned short* __restrict__ Sbf, float* __restrict__ rv)
{
    int bid = blockIdx.x, t = threadIdx.x;
    if (bid < 128) {
        int b = bid >> 4, sl = bid & 15;
        int base = sl*4096 + t*8;
        float s[8] = {0.f,0.f,0.f,0.f,0.f,0.f,0.f,0.f};
        #pragma unroll
        for (int i = 0; i < 16; ++i) {
            u16x8 v = *(const u16x8*)(Sp + (size_t)(b*16 + i)*65536 + base);
            #pragma unroll
            for (int e = 0; e < 8; ++e) s[e] += bf2f(v[e]);
        }
        u16x8 o;
        #pragma unroll
        for (int e = 0; e < 8; ++e) o[e] = f2bf(s[e]);
        *(u16x8*)(Sbf + (size_t)b*65536 + base) = o;
    } else {
        int b = bid - 128;
        if (t < 256) {
            float s = 0.f;
            #pragma unroll
            for (int i = 0; i < 16; ++i) s += Rp[(b*16 + i)*256 + t];
            rv[b*256 + t] = s;
        }
    }
}

// ============ kE: 32 blocks (b, o-slice of 64). Y=A_sl*S; E=(Y*Cm)/N + rank-2; f; BN stats ============
__global__ __launch_bounds__(512) void kE(
    const unsigned short* __restrict__ Sbf, const float* __restrict__ rv,
    const unsigned short* __restrict__ Abf, const unsigned short* __restrict__ CmT,
    const float* __restrict__ a1g, const float* __restrict__ c1vg, const float* __restrict__ p2g,
    const float* __restrict__ params, const float* __restrict__ Wbv,
    unsigned short* __restrict__ Ebf, float* __restrict__ fv, float* __restrict__ stats)
{
    __shared__ __align__(16) unsigned short Ybuf[16384];  // [64][256] swz
    __shared__ __align__(16) unsigned short Ebuf[16384];  // [64][256] swz
    __shared__ float r_l[256], p2_l[256], c1v_l[256], cr[256];
    __shared__ float a1_l[64], ar[64], Yp2[64], er[64], diag_l[64];
    __shared__ float rp2_s;
    int blk = blockIdx.x;
    int b = blk >> 2, obase = (blk & 3) * 64;
    int t = threadIdx.x, lane = t & 63, wv = t >> 6;
    int lr = lane & 15, lg = lane >> 4;
    const float invN = 1.0f/4096.0f;
    const unsigned short* Sb = Sbf + (size_t)b*65536;

    if (t < 256) {
        r_l[t] = rv[b*256 + t];
        p2_l[t] = p2g[t];
        c1v_l[t] = c1vg[t];
    } else if (t < 320) {
        a1_l[t - 256] = a1g[obase + (t - 256)];
    }
    __syncthreads();

    // GEMM1: Y[64][256] = A_sl * S
    f32x4 acc[4][2];
    #pragma unroll
    for (int i = 0; i < 4; ++i) { acc[i][0] = (f32x4){0,0,0,0}; acc[i][1] = (f32x4){0,0,0,0}; }
    const unsigned short* Arow0 = Abf + (size_t)obase*256;
    #pragma unroll
    for (int ks = 0; ks < 8; ++ks) {
        bf16x8 a4[4], b2[2];
        #pragma unroll
        for (int mi = 0; mi < 4; ++mi)
            a4[mi] = __builtin_bit_cast(bf16x8, *(const u16x8*)(Arow0 + (size_t)(mi*16+lr)*256 + ks*32 + lg*8));
        #pragma unroll
        for (int ni = 0; ni < 2; ++ni)
            b2[ni] = __builtin_bit_cast(bf16x8, *(const u16x8*)(Sb + (size_t)(wv*32+ni*16+lr)*256 + ks*32 + lg*8));
        #pragma unroll
        for (int mi = 0; mi < 4; ++mi)
            #pragma unroll
            for (int ni = 0; ni < 2; ++ni)
                acc[mi][ni] = MFMA(a4[mi], b2[ni], acc[mi][ni]);
    }
    #pragma unroll
    for (int mi = 0; mi < 4; ++mi)
        #pragma unroll
        for (int ni = 0; ni < 2; ++ni)
            #pragma unroll
            for (int j = 0; j < 4; ++j) {
                int ol = mi*16 + lg*4 + j;
                int c2 = wv*32 + ni*16 + lr;
                Ybuf[ol*256 + (c2 ^ ((ol&7)<<3))] = f2bf(acc[mi][ni][j]);
            }
    __syncthreads();

    {
        int row = t >> 3, p8 = t & 7;
        float sA = 0.f, sY = 0.f;
        const unsigned short* Ar = Abf + (size_t)(obase + row)*256 + p8*32;
        #pragma unroll
        for (int q = 0; q < 4; ++q) {
            u16x8 av = *(const u16x8*)(Ar + q*8);
            #pragma unroll
            for (int e = 0; e < 8; ++e) {
                int c = p8*32 + q*8 + e;
                sA += bf2f(av[e]) * r_l[c];
                sY += bf2f(Ybuf[row*256 + (c ^ ((row&7)<<3))]) * p2_l[c];
            }
        }
        sA += __shfl_xor(sA, 1); sA += __shfl_xor(sA, 2); sA += __shfl_xor(sA, 4);
        sY += __shfl_xor(sY, 1); sY += __shfl_xor(sY, 2); sY += __shfl_xor(sY, 4);
        if (p8 == 0) { ar[row] = sA; Yp2[row] = sY; }
    }
    if (t < 256) {
        float s = 0.f;
        const unsigned short* Cr = CmT + (size_t)t*256;
        #pragma unroll
        for (int q = 0; q < 32; ++q) {
            u16x8 v = *(const u16x8*)(Cr + q*8);
            #pragma unroll
            for (int e = 0; e < 8; ++e) s += bf2f(v[e]) * r_l[q*8 + e];
        }
        cr[t] = s;
    }
    if (t < 64) {
        float v = r_l[t*4]*p2_l[t*4] + r_l[t*4+1]*p2_l[t*4+1]
                + r_l[t*4+2]*p2_l[t*4+2] + r_l[t*4+3]*p2_l[t*4+3];
        #pragma unroll
        for (int off = 1; off < 64; off <<= 1) v += __shfl_xor(v, off);
        if (t == 0) rp2_s = v;
    }
    __syncthreads();

    // GEMM2: E = (Y*Cm)/N + a1*cr^T/N + (ar/N + a1)*c1v^T
    f32x4 accE[4][2];
    #pragma unroll
    for (int i = 0; i < 4; ++i) { accE[i][0] = (f32x4){0,0,0,0}; accE[i][1] = (f32x4){0,0,0,0}; }
    #pragma unroll
    for (int ks = 0; ks < 8; ++ks) {
        bf16x8 a4[4], b2[2];
        #pragma unroll
        for (int mi = 0; mi < 4; ++mi) {
            int ol = mi*16 + lr;
            a4[mi] = __builtin_bit_cast(bf16x8, *(const u16x8*)&Ybuf[ol*256 + ((ks*32 + lg*8) ^ ((ol&7)<<3))]);
        }
        #pragma unroll
        for (int ni = 0; ni < 2; ++ni)
            b2[ni] = __builtin_bit_cast(bf16x8, *(const u16x8*)(CmT + (size_t)(wv*32+ni*16+lr)*256 + ks*32 + lg*8));
        #pragma unroll
        for (int mi = 0; mi < 4; ++mi)
            #pragma unroll
            for (int ni = 0; ni < 2; ++ni)
                accE[mi][ni] = MFMA(a4[mi], b2[ni], accE[mi][ni]);
    }
    unsigned short* Eb = Ebf + (size_t)b*65536;
    #pragma unroll
    for (int mi = 0; mi < 4; ++mi)
        #pragma unroll
        for (int ni = 0; ni < 2; ++ni)
            #pragma unroll
            for (int j = 0; j < 4; ++j) {
                int ol = mi*16 + lg*4 + j;
                int cp = wv*32 + ni*16 + lr;
                float e = accE[mi][ni][j]*invN + a1_l[ol]*invN*cr[cp]
                        + (invN*ar[ol] + a1_l[ol])*c1v_l[cp];
                unsigned short eb = f2bf(e);
                Ebuf[ol*256 + (cp ^ ((ol&7)<<3))] = eb;
                Eb[(size_t)(obase + ol)*256 + cp] = eb;
            }
    __syncthreads();

    float f_reg = 0.f;
    {
        int row = t >> 3, p8 = t & 7;
        float s = 0.f;
        #pragma unroll
        for (int q = 0; q < 4; ++q)
            #pragma unroll
            for (int e = 0; e < 8; ++e) {
                int c = p8*32 + q*8 + e;
                s += bf2f(Ebuf[row*256 + (c ^ ((row&7)<<3))]) * r_l[c];
            }
        s += __shfl_xor(s, 1); s += __shfl_xor(s, 2); s += __shfl_xor(s, 4);
        if (p8 == 0) er[row] = s;
    }
    if (t < 64) {
        diag_l[t] = 0.f;
        float sg = params[0];
        f_reg = invN*(Yp2[t] + a1_l[t]*rp2_s + ar[t]*sg) + a1_l[t]*sg + Wbv[obase + t];
        fv[b*256 + obase + t] = f_reg;
    }
    __syncthreads();

    // GEMM3: Z = E_sl * S ; diag[o] = sum_c2 Z[o][c2]*E[o][c2]
    f32x4 accZ[4][2];
    #pragma unroll
    for (int i = 0; i < 4; ++i) { accZ[i][0] = (f32x4){0,0,0,0}; accZ[i][1] = (f32x4){0,0,0,0}; }
    #pragma unroll
    for (int ks = 0; ks < 8; ++ks) {
        bf16x8 a4[4], b2[2];
        #pragma unroll
        for (int mi = 0; mi < 4; ++mi) {
            int ol = mi*16 + lr;
            a4[mi] = __builtin_bit_cast(bf16x8, *(const u16x8*)&Ebuf[ol*256 + ((ks*32 + lg*8) ^ ((ol&7)<<3))]);
        }
        #pragma unroll
        for (int ni = 0; ni < 2; ++ni)
            b2[ni] = __builtin_bit_cast(bf16x8, *(const u16x8*)(Sb + (size_t)(wv*32+ni*16+lr)*256 + ks*32 + lg*8));
        #pragma unroll
        for (int mi = 0; mi < 4; ++mi)
            #pragma unroll
            for (int ni = 0; ni < 2; ++ni)
                accZ[mi][ni] = MFMA(a4[mi], b2[ni], accZ[mi][ni]);
    }
    #pragma unroll
    for (int mi = 0; mi < 4; ++mi)
        #pragma unroll
        for (int j = 0; j < 4; ++j) {
            int ol = mi*16 + lg*4 + j;
            float s = 0.f;
            #pragma unroll
            for (int ni = 0; ni < 2; ++ni) {
                int c2 = wv*32 + ni*16 + lr;
                s += accZ[mi][ni][j] * bf2f(Ebuf[ol*256 + (c2 ^ ((ol&7)<<3))]);
            }
            s += __shfl_xor(s, 1); s += __shfl_xor(s, 2);
            s += __shfl_xor(s, 4); s += __shfl_xor(s, 8);
            if (lr == 0) atomicAdd(&diag_l[ol], s);
        }
    __syncthreads();

    if (t < 64) {
        int o = obase + t;
        atomicAdd(&stats[o], er[t] + 4096.0f*f_reg);
        atomicAdd(&stats[256 + o], diag_l[t] + 2.0f*f_reg*er[t] + 4096.0f*f_reg*f_reg);
    }
}

// ============ kF: out = (E x + f - mu)*gamma*rsqrt(var+eps) + beta + x  (coalesced stores) ============
__global__ __launch_bounds__(512) void kF(
    const float* __restrict__ x, const unsigned short* __restrict__ Ebf,
    const float* __restrict__ fv, const float* __restrict__ stats,
    const float* __restrict__ gamma, const float* __restrict__ beta,
    float* __restrict__ out)
{
    __shared__ __align__(16) unsigned short Xs[128*256];  // 64 KB, [n][c] swz
    __shared__ float scale_l[256], shift_l[256];
    int b = blockIdx.x >> 5, n0 = (blockIdx.x & 31) * 128;
    int t = threadIdx.x, lane = t & 63, wv = t >> 6, lr = lane & 15, lg = lane >> 4;
    const float inv = 1.0f / 32768.0f;
    if (t < 256) {
        float mu  = stats[t] * inv;
        float var = stats[256 + t] * inv - mu*mu;
        float sc  = gamma[t] * rsqrtf(var + 1e-5f);
        scale_l[t] = sc;
        shift_l[t] = (fv[b*256 + t] - mu) * sc + beta[t];
    }
    {
        int nq = (t & 31) * 4, c0 = (t >> 5) * 4;
        const float* xb = x + (size_t)b*CIN*NN + n0 + nq;
        #pragma unroll
        for (int p = 0; p < 4; ++p) {
            int c = p*64 + c0;
            const float* xp = xb + (size_t)c*NN;
            float4 f0 = *(const float4*)(xp);
            float4 f1 = *(const float4*)(xp + NN);
            float4 f2 = *(const float4*)(xp + 2*NN);
            float4 f3 = *(const float4*)(xp + 3*NN);
            *(ushort4*)&Xs[(nq+0)*256 + (c ^ (((nq+0)&7)<<3))] = pack4(f0.x,f1.x,f2.x,f3.x);
            *(ushort4*)&Xs[(nq+1)*256 + (c ^ (((nq+1)&7)<<3))] = pack4(f0.y,f1.y,f2.y,f3.y);
            *(ushort4*)&Xs[(nq+2)*256 + (c ^ (((nq+2)&7)<<3))] = pack4(f0.z,f1.z,f2.z,f3.z);
            *(ushort4*)&Xs[(nq+3)*256 + (c ^ (((nq+3)&7)<<3))] = pack4(f0.w,f1.w,f2.w,f3.w);
        }
    }
    __syncthreads();

    int wn = wv >> 2, wo = wv & 3;
    int nb = wn*64, ob = wo*64;
    const unsigned short* Eb = Ebf + (size_t)b*65536;
    f32x4 acc[4][4];   // [oi][ni]
    #pragma unroll
    for (int i = 0; i < 4; ++i)
        #pragma unroll
        for (int j = 0; j < 4; ++j) acc[i][j] = (f32x4){0,0,0,0};

    #pragma unroll
    for (int ks = 0; ks < 8; ++ks) {
        bf16x8 xf[4], ef[4];
        #pragma unroll
        for (int ni = 0; ni < 4; ++ni) {
            int n = nb + ni*16 + lr;
            xf[ni] = __builtin_bit_cast(bf16x8, *(const u16x8*)&Xs[(n*256 + ks*32 + lg*8) ^ ((n&7)<<3)]);
        }
        #pragma unroll
        for (int oi = 0; oi < 4; ++oi) {
            int o = ob + oi*16 + lr;
            ef[oi] = __builtin_bit_cast(bf16x8, *(const u16x8*)(Eb + (size_t)o*256 + ks*32 + lg*8));
        }
        #pragma unroll
        for (int oi = 0; oi < 4; ++oi)
            #pragma unroll
            for (int ni = 0; ni < 4; ++ni)
                acc[oi][ni] = MFMA(ef[oi], xf[ni], acc[oi][ni]);
    }

    float* op = out + (size_t)b*CIN*NN + n0;
    #pragma unroll
    for (int oi = 0; oi < 4; ++oi) {
        #pragma unroll
        for (int j = 0; j < 4; ++j) {
            int o = ob + oi*16 + lg*4 + j;
            float sc = scale_l[o], sh = shift_l[o];
            #pragma unroll
            for (int ni = 0; ni < 4; ++ni) {
                int n = nb + ni*16 + lr;
                float val = acc[oi][ni][j]*sc + sh + bf2f(Xs[(n*256 + (o ^ ((n&7)<<3)))]);
                op[(size_t)o*NN + n] = val;
            }
        }
    }
}

extern "C" void kernel_launch(void* const* d_in, const int* in_sizes, int n_in,
                              void* d_out, int out_size, void* d_ws, size_t ws_size,
                              hipStream_t stream)
{
    (void)in_sizes; (void)n_in; (void)out_size; (void)ws_size;
    const float* x     = (const float*)d_in[0];
    const float* gw    = (const float*)d_in[1];
    const float* gb    = (const float*)d_in[2];
    const float* tw    = (const float*)d_in[3];
    const float* tb    = (const float*)d_in[4];
    const float* pw    = (const float*)d_in[5];
    const float* pb    = (const float*)d_in[6];
    const float* Ww    = (const float*)d_in[7];
    const float* Wb    = (const float*)d_in[8];
    const float* gamma = (const float*)d_in[9];
    const float* beta  = (const float*)d_in[10];
    float* out = (float*)d_out;

    char* ws = (char*)d_ws;
    unsigned short* Sp  = (unsigned short*)(ws + 0);          // 16 MB
    float* Rp           = (float*)(ws + 16777216);            // 128 KB
    unsigned short* Sbf = (unsigned short*)(ws + 16908288);   // 1 MB
    float* rv           = (float*)(ws + 17956864);            // 8 KB
    unsigned short* Abf = (unsigned short*)(ws + 17965056);   // 128 KB
    unsigned short* CmT = (unsigned short*)(ws + 18096128);   // 128 KB
    unsigned short* Ebf = (unsigned short*)(ws + 18227200);   // 1 MB
    float* fv           = (float*)(ws + 19275776);            // 8 KB
    float* a1           = (float*)(ws + 19283968);            // 1 KB
    float* c1v          = (float*)(ws + 19284992);            // 1 KB
    float* p2           = (float*)(ws + 19286016);            // 1 KB
    float* params       = (float*)(ws + 19287040);            // 64 B
    float* stats        = (float*)(ws + 19287104);            // 2 KB

    kA<<<130, 512, 0, stream>>>(x, Ww, gw, tw, pw, gb, pb, tb,
                                Sp, Rp, Abf, CmT, a1, c1v, p2, params, stats);
    kR<<<136, 512, 0, stream>>>(Sp, Rp, Sbf, rv);
    kE<<<32,  512, 0, stream>>>(Sbf, rv, Abf, CmT, a1, c1v, p2, params, Wb, Ebf, fv, stats);
    kF<<<256, 512, 0, stream>>>(x, Ebf, fv, stats, gamma, beta, out);
}

// Round 9
// 83.092 us; speedup vs baseline: 2.4446x; 1.0014x over previous
//
#include <hip/hip_runtime.h>
#include <hip/hip_bf16.h>
#include <stdint.h>

#define BB   8
#define CIN  256
#define COUT 128
#define NN   4096

using f32x4  = __attribute__((ext_vector_type(4))) float;
using bf16x8 = __attribute__((ext_vector_type(8))) __bf16;
using u16x8  = __attribute__((ext_vector_type(8))) unsigned short;

static __device__ __forceinline__ unsigned short f2bf(float f) {
    unsigned int u = __builtin_bit_cast(unsigned int, f);
    u += 0x7FFFu + ((u >> 16) & 1u);
    return (unsigned short)(u >> 16);
}
static __device__ __forceinline__ float bf2f(unsigned short u) {
    return __builtin_bit_cast(float, (unsigned int)u << 16);
}
static __device__ __forceinline__ ushort4 pack4(float a, float b, float c, float d) {
    ushort4 r; r.x=f2bf(a); r.y=f2bf(b); r.z=f2bf(c); r.w=f2bf(d); return r;
}
#define MFMA(a,b,c) __builtin_amdgcn_mfma_f32_16x16x32_bf16((a),(b),(c),0,0,0)

static __device__ __forceinline__ int sw256(int r, int c) { return (r*256 + c) ^ ((r&7)<<3); }
static __device__ __forceinline__ int sw128(int r, int c) { return (r*128 + c) ^ ((r&7)<<3); }

// ============ kA: 130 blocks.
//   0-127: Gram partials Sp[bid] (bf16) + Rp (row-sums from LDS, off load path)
//   128  : Abf = Ww*Gw, a1 = Ww*gb, zero stats
//   129  : CmT = Tw^T*Pw, c1v = Tw^T*pb, p2 = Pw^T*tb, sigma ============
__global__ __launch_bounds__(512) void kA(
    const float* __restrict__ x,
    const float* __restrict__ Wwf, const float* __restrict__ gwf,
    const float* __restrict__ twf, const float* __restrict__ pwf,
    const float* __restrict__ gbv, const float* __restrict__ pbv, const float* __restrict__ tbv,
    unsigned short* __restrict__ Sp, float* __restrict__ Rp,
    unsigned short* __restrict__ Abf, unsigned short* __restrict__ CmT,
    float* __restrict__ a1, float* __restrict__ c1v, float* __restrict__ p2,
    float* __restrict__ params, float* __restrict__ stats)
{
    __shared__ __align__(16) unsigned short SH[65536];   // 128 KB
    int bid = blockIdx.x;
    int t = threadIdx.x, lane = t & 63, wv = t >> 6;
    int lr = lane & 15, lg = lane >> 4;

    if (bid < 128) {
        int b = bid >> 4, ch = bid & 15;
        int n0 = ch * 256;
        const float* xb = x + (size_t)b*CIN*NN + n0 + lane*4;
        // two-phase staging: 16 loads in flight, then convert+write
        #pragma unroll
        for (int g = 0; g < 2; ++g) {
            float4 v[16];
            #pragma unroll
            for (int i = 0; i < 16; ++i) {
                int c = wv*32 + g*16 + i;
                v[i] = *(const float4*)(xb + (size_t)c*NN);
            }
            #pragma unroll
            for (int i = 0; i < 16; ++i) {
                int c = wv*32 + g*16 + i;
                *(ushort4*)&SH[sw256(c, lane*4)] = pack4(v[i].x, v[i].y, v[i].z, v[i].w);
            }
        }
        __syncthreads();

        int wr = wv >> 1, wc = wv & 1;      // 4x2: tile 64 x 128
        f32x4 acc[4][8];
        #pragma unroll
        for (int i = 0; i < 4; ++i)
            #pragma unroll
            for (int j = 0; j < 8; ++j) acc[i][j] = (f32x4){0.f,0.f,0.f,0.f};
        #pragma unroll
        for (int ks = 0; ks < 8; ++ks) {
            bf16x8 af[4], bfr[8];
            #pragma unroll
            for (int mi = 0; mi < 4; ++mi) {
                int row = wr*64 + mi*16 + lr;
                af[mi] = __builtin_bit_cast(bf16x8, *(const u16x8*)&SH[sw256(row, ks*32 + lg*8)]);
            }
            #pragma unroll
            for (int ni = 0; ni < 8; ++ni) {
                int row = wc*128 + ni*16 + lr;
                bfr[ni] = __builtin_bit_cast(bf16x8, *(const u16x8*)&SH[sw256(row, ks*32 + lg*8)]);
            }
            #pragma unroll
            for (int mi = 0; mi < 4; ++mi)
                #pragma unroll
                for (int ni = 0; ni < 8; ++ni)
                    acc[mi][ni] = MFMA(af[mi], bfr[ni], acc[mi][ni]);
        }
        // row-sums from LDS (off the load critical path)
        if (t < 256) {
            float s = 0.f;
            #pragma unroll
            for (int q = 0; q < 32; ++q) {
                u16x8 vv = *(const u16x8*)&SH[sw256(t, q*8)];
                #pragma unroll
                for (int e = 0; e < 8; ++e) s += bf2f(vv[e]);
            }
            Rp[bid*256 + t] = s;
        }
        __syncthreads();   // all SH reads complete before overwrite
        // dump acc -> SH (swizzled)
        #pragma unroll
        for (int mi = 0; mi < 4; ++mi)
            #pragma unroll
            for (int ni = 0; ni < 8; ++ni)
                #pragma unroll
                for (int j = 0; j < 4; ++j) {
                    int c1 = wr*64 + mi*16 + lg*4 + j;
                    int c2 = wc*128 + ni*16 + lr;
                    SH[sw256(c1, c2)] = f2bf(acc[mi][ni][j]);
                }
        __syncthreads();
        // coalesced u16x8 store: 512B contiguous per row
        unsigned short* dst = Sp + (size_t)bid * 65536;
        #pragma unroll
        for (int i = t; i < 8192; i += 512) {
            int row = i >> 5, q = i & 31;
            *(u16x8*)(dst + row*256 + ((q ^ (row&7)) * 8)) = *(const u16x8*)&SH[row*256 + q*8];
        }
        return;
    }

    // ---- weight precompute blocks ----
    unsigned short* Ls = SH;
    unsigned short* Rs = SH + 32768;
    if (bid == 128) {
        for (int i = t; i < 8192; i += 512) {
            int flat = i*4, r = flat >> 7, c = flat & 127;
            float4 f = *(const float4*)(Wwf + flat);
            *(ushort4*)&Ls[sw128(r, c)] = pack4(f.x, f.y, f.z, f.w);
        }
        {
            int c = lane * 4;  int k4 = wv * 4;
            #pragma unroll
            for (int rep = 0; rep < 4; ++rep) {
                int kb = rep*32 + k4;
                float4 f0 = *(const float4*)(gwf + (size_t)(kb+0)*256 + c);
                float4 f1 = *(const float4*)(gwf + (size_t)(kb+1)*256 + c);
                float4 f2 = *(const float4*)(gwf + (size_t)(kb+2)*256 + c);
                float4 f3 = *(const float4*)(gwf + (size_t)(kb+3)*256 + c);
                *(ushort4*)&Rs[sw128(c+0, kb)] = pack4(f0.x, f1.x, f2.x, f3.x);
                *(ushort4*)&Rs[sw128(c+1, kb)] = pack4(f0.y, f1.y, f2.y, f3.y);
                *(ushort4*)&Rs[sw128(c+2, kb)] = pack4(f0.z, f1.z, f2.z, f3.z);
                *(ushort4*)&Rs[sw128(c+3, kb)] = pack4(f0.w, f1.w, f2.w, f3.w);
            }
        }
        if (t < 512) stats[t] = 0.f;
    } else {
        {
            int c = lane * 4;  int k4 = wv * 4;
            #pragma unroll
            for (int rep = 0; rep < 4; ++rep) {
                int kb = rep*32 + k4;
                float4 f0 = *(const float4*)(twf + (size_t)(kb+0)*256 + c);
                float4 f1 = *(const float4*)(twf + (size_t)(kb+1)*256 + c);
                float4 f2 = *(const float4*)(twf + (size_t)(kb+2)*256 + c);
                float4 f3 = *(const float4*)(twf + (size_t)(kb+3)*256 + c);
                *(ushort4*)&Ls[sw128(c+0, kb)] = pack4(f0.x, f1.x, f2.x, f3.x);
                *(ushort4*)&Ls[sw128(c+1, kb)] = pack4(f0.y, f1.y, f2.y, f3.y);
                *(ushort4*)&Ls[sw128(c+2, kb)] = pack4(f0.z, f1.z, f2.z, f3.z);
                *(ushort4*)&Ls[sw128(c+3, kb)] = pack4(f0.w, f1.w, f2.w, f3.w);
                float4 g0 = *(const float4*)(pwf + (size_t)(kb+0)*256 + c);
                float4 g1 = *(const float4*)(pwf + (size_t)(kb+1)*256 + c);
                float4 g2 = *(const float4*)(pwf + (size_t)(kb+2)*256 + c);
                float4 g3 = *(const float4*)(pwf + (size_t)(kb+3)*256 + c);
                *(ushort4*)&Rs[sw128(c+0, kb)] = pack4(g0.x, g1.x, g2.x, g3.x);
                *(ushort4*)&Rs[sw128(c+1, kb)] = pack4(g0.y, g1.y, g2.y, g3.y);
                *(ushort4*)&Rs[sw128(c+2, kb)] = pack4(g0.z, g1.z, g2.z, g3.z);
                *(ushort4*)&Rs[sw128(c+3, kb)] = pack4(g0.w, g1.w, g2.w, g3.w);
            }
        }
    }
    __syncthreads();

    int wr = wv >> 2, wc = wv & 3;      // 2x4: tile 128 x 64
    f32x4 acc[8][4];
    #pragma unroll
    for (int i = 0; i < 8; ++i)
        #pragma unroll
        for (int j = 0; j < 4; ++j) acc[i][j] = (f32x4){0.f,0.f,0.f,0.f};
    #pragma unroll
    for (int ks = 0; ks < 4; ++ks) {
        bf16x8 af[8], bfr[4];
        #pragma unroll
        for (int mi = 0; mi < 8; ++mi) {
            int r = wr*128 + mi*16 + lr;
            af[mi] = __builtin_bit_cast(bf16x8, *(const u16x8*)&Ls[sw128(r, ks*32 + lg*8)]);
        }
        #pragma unroll
        for (int ni = 0; ni < 4; ++ni) {
            int c = wc*64 + ni*16 + lr;
            bfr[ni] = __builtin_bit_cast(bf16x8, *(const u16x8*)&Rs[sw128(c, ks*32 + lg*8)]);
        }
        #pragma unroll
        for (int mi = 0; mi < 8; ++mi)
            #pragma unroll
            for (int ni = 0; ni < 4; ++ni)
                acc[mi][ni] = MFMA(af[mi], bfr[ni], acc[mi][ni]);
    }
    unsigned short* Dst = (bid == 128) ? Abf : CmT;
    #pragma unroll
    for (int mi = 0; mi < 8; ++mi)
        #pragma unroll
        for (int ni = 0; ni < 4; ++ni)
            #pragma unroll
            for (int j = 0; j < 4; ++j) {
                int r = wr*128 + mi*16 + lg*4 + j;
                int c = wc*64 + ni*16 + lr;
                Dst[r*256 + c] = f2bf(acc[mi][ni][j]);
            }

    if (bid == 128) {
        if (t < 256) {
            float s = 0.f;
            #pragma unroll
            for (int q = 0; q < 32; ++q) {
                float4 f = *(const float4*)(Wwf + (size_t)t*128 + q*4);
                s += f.x*gbv[q*4] + f.y*gbv[q*4+1] + f.z*gbv[q*4+2] + f.w*gbv[q*4+3];
            }
            a1[t] = s;
        }
    } else {
        if (t < 256) {
            float s1 = 0.f, s2 = 0.f;
            for (int k = 0; k < 128; ++k) {
                s1 += twf[(size_t)k*256 + t] * pbv[k];
                s2 += pwf[(size_t)k*256 + t] * tbv[k];
            }
            c1v[t] = s1; p2[t] = s2;
        }
        if (t < 64) {
            float v = pbv[t]*tbv[t] + pbv[t+64]*tbv[t+64];
            #pragma unroll
            for (int off = 1; off < 64; off <<= 1) v += __shfl_xor(v, off);
            if (t == 0) params[0] = v;
        }
    }
}

// ============ kR: 136 blocks. 0-127: Sbf[b] = sum 16 partials; 128-135: rv ============
__global__ __launch_bounds__(512) void kR(
    const unsigned short* __restrict__ Sp, const float* __restrict__ Rp,
    unsigned short* __restrict__ Sbf, float* __restrict__ rv)
{
    int bid = blockIdx.x, t = threadIdx.x;
    if (bid < 128) {
        int b = bid >> 4, sl = bid & 15;
        int base = sl*4096 + t*8;
        float s[8] = {0.f,0.f,0.f,0.f,0.f,0.f,0.f,0.f};
        #pragma unroll
        for (int i = 0; i < 16; ++i) {
            u16x8 v = *(const u16x8*)(Sp + (size_t)(b*16 + i)*65536 + base);
            #pragma unroll
            for (int e = 0; e < 8; ++e) s[e] += bf2f(v[e]);
        }
        u16x8 o;
        #pragma unroll
        for (int e = 0; e < 8; ++e) o[e] = f2bf(s[e]);
        *(u16x8*)(Sbf + (size_t)b*65536 + base) = o;
    } else {
        int b = bid - 128;
        if (t < 256) {
            float s = 0.f;
            #pragma unroll
            for (int i = 0; i < 16; ++i) s += Rp[(b*16 + i)*256 + t];
            rv[b*256 + t] = s;
        }
    }
}

// ============ kE: 32 blocks (b, o-slice of 64). Y=A_sl*S; E=(Y*Cm)/N + rank-2; f; BN stats ============
__global__ __launch_bounds__(512) void kE(
    const unsigned short* __restrict__ Sbf, const float* __restrict__ rv,
    const unsigned short* __restrict__ Abf, const unsigned short* __restrict__ CmT,
    const float* __restrict__ a1g, const float* __restrict__ c1vg, const float* __restrict__ p2g,
    const float* __restrict__ params, const float* __restrict__ Wbv,
    unsigned short* __restrict__ Ebf, float* __restrict__ fv, float* __restrict__ stats)
{
    __shared__ __align__(16) unsigned short Ybuf[16384];  // [64][256] swz
    __shared__ __align__(16) unsigned short Ebuf[16384];  // [64][256] swz
    __shared__ float r_l[256], p2_l[256], c1v_l[256], cr[256];
    __shared__ float a1_l[64], ar[64], Yp2[64], er[64], diag_l[64];
    __shared__ float rp2_s;
    int blk = blockIdx.x;
    int b = blk >> 2, obase = (blk & 3) * 64;
    int t = threadIdx.x, lane = t & 63, wv = t >> 6;
    int lr = lane & 15, lg = lane >> 4;
    const float invN = 1.0f/4096.0f;
    const unsigned short* Sb = Sbf + (size_t)b*65536;

    if (t < 256) {
        r_l[t] = rv[b*256 + t];
        p2_l[t] = p2g[t];
        c1v_l[t] = c1vg[t];
    } else if (t < 320) {
        a1_l[t - 256] = a1g[obase + (t - 256)];
    }
    __syncthreads();

    // GEMM1: Y[64][256] = A_sl * S
    f32x4 acc[4][2];
    #pragma unroll
    for (int i = 0; i < 4; ++i) { acc[i][0] = (f32x4){0,0,0,0}; acc[i][1] = (f32x4){0,0,0,0}; }
    const unsigned short* Arow0 = Abf + (size_t)obase*256;
    #pragma unroll
    for (int ks = 0; ks < 8; ++ks) {
        bf16x8 a4[4], b2[2];
        #pragma unroll
        for (int mi = 0; mi < 4; ++mi)
            a4[mi] = __builtin_bit_cast(bf16x8, *(const u16x8*)(Arow0 + (size_t)(mi*16+lr)*256 + ks*32 + lg*8));
        #pragma unroll
        for (int ni = 0; ni < 2; ++ni)
            b2[ni] = __builtin_bit_cast(bf16x8, *(const u16x8*)(Sb + (size_t)(wv*32+ni*16+lr)*256 + ks*32 + lg*8));
        #pragma unroll
        for (int mi = 0; mi < 4; ++mi)
            #pragma unroll
            for (int ni = 0; ni < 2; ++ni)
                acc[mi][ni] = MFMA(a4[mi], b2[ni], acc[mi][ni]);
    }
    #pragma unroll
    for (int mi = 0; mi < 4; ++mi)
        #pragma unroll
        for (int ni = 0; ni < 2; ++ni)
            #pragma unroll
            for (int j = 0; j < 4; ++j) {
                int ol = mi*16 + lg*4 + j;
                int c2 = wv*32 + ni*16 + lr;
                Ybuf[ol*256 + (c2 ^ ((ol&7)<<3))] = f2bf(acc[mi][ni][j]);
            }
    __syncthreads();

    {
        int row = t >> 3, p8 = t & 7;
        float sA = 0.f, sY = 0.f;
        const unsigned short* Ar = Abf + (size_t)(obase + row)*256 + p8*32;
        #pragma unroll
        for (int q = 0; q < 4; ++q) {
            u16x8 av = *(const u16x8*)(Ar + q*8);
            #pragma unroll
            for (int e = 0; e < 8; ++e) {
                int c = p8*32 + q*8 + e;
                sA += bf2f(av[e]) * r_l[c];
                sY += bf2f(Ybuf[row*256 + (c ^ ((row&7)<<3))]) * p2_l[c];
            }
        }
        sA += __shfl_xor(sA, 1); sA += __shfl_xor(sA, 2); sA += __shfl_xor(sA, 4);
        sY += __shfl_xor(sY, 1); sY += __shfl_xor(sY, 2); sY += __shfl_xor(sY, 4);
        if (p8 == 0) { ar[row] = sA; Yp2[row] = sY; }
    }
    if (t < 256) {
        float s = 0.f;
        const unsigned short* Cr = CmT + (size_t)t*256;
        #pragma unroll
        for (int q = 0; q < 32; ++q) {
            u16x8 v = *(const u16x8*)(Cr + q*8);
            #pragma unroll
            for (int e = 0; e < 8; ++e) s += bf2f(v[e]) * r_l[q*8 + e];
        }
        cr[t] = s;
    }
    if (t < 64) {
        float v = r_l[t*4]*p2_l[t*4] + r_l[t*4+1]*p2_l[t*4+1]
                + r_l[t*4+2]*p2_l[t*4+2] + r_l[t*4+3]*p2_l[t*4+3];
        #pragma unroll
        for (int off = 1; off < 64; off <<= 1) v += __shfl_xor(v, off);
        if (t == 0) rp2_s = v;
    }
    __syncthreads();

    // GEMM2: E = (Y*Cm)/N + a1*cr^T/N + (ar/N + a1)*c1v^T
    f32x4 accE[4][2];
    #pragma unroll
    for (int i = 0; i < 4; ++i) { accE[i][0] = (f32x4){0,0,0,0}; accE[i][1] = (f32x4){0,0,0,0}; }
    #pragma unroll
    for (int ks = 0; ks < 8; ++ks) {
        bf16x8 a4[4], b2[2];
        #pragma unroll
        for (int mi = 0; mi < 4; ++mi) {
            int ol = mi*16 + lr;
            a4[mi] = __builtin_bit_cast(bf16x8, *(const u16x8*)&Ybuf[ol*256 + ((ks*32 + lg*8) ^ ((ol&7)<<3))]);
        }
        #pragma unroll
        for (int ni = 0; ni < 2; ++ni)
            b2[ni] = __builtin_bit_cast(bf16x8, *(const u16x8*)(CmT + (size_t)(wv*32+ni*16+lr)*256 + ks*32 + lg*8));
        #pragma unroll
        for (int mi = 0; mi < 4; ++mi)
            #pragma unroll
            for (int ni = 0; ni < 2; ++ni)
                accE[mi][ni] = MFMA(a4[mi], b2[ni], accE[mi][ni]);
    }
    unsigned short* Eb = Ebf + (size_t)b*65536;
    #pragma unroll
    for (int mi = 0; mi < 4; ++mi)
        #pragma unroll
        for (int ni = 0; ni < 2; ++ni)
            #pragma unroll
            for (int j = 0; j < 4; ++j) {
                int ol = mi*16 + lg*4 + j;
                int cp = wv*32 + ni*16 + lr;
                float e = accE[mi][ni][j]*invN + a1_l[ol]*invN*cr[cp]
                        + (invN*ar[ol] + a1_l[ol])*c1v_l[cp];
                unsigned short eb = f2bf(e);
                Ebuf[ol*256 + (cp ^ ((ol&7)<<3))] = eb;
                Eb[(size_t)(obase + ol)*256 + cp] = eb;
            }
    __syncthreads();

    float f_reg = 0.f;
    {
        int row = t >> 3, p8 = t & 7;
        float s = 0.f;
        #pragma unroll
        for (int q = 0; q < 4; ++q)
            #pragma unroll
            for (int e = 0; e < 8; ++e) {
                int c = p8*32 + q*8 + e;
                s += bf2f(Ebuf[row*256 + (c ^ ((row&7)<<3))]) * r_l[c];
            }
        s += __shfl_xor(s, 1); s += __shfl_xor(s, 2); s += __shfl_xor(s, 4);
        if (p8 == 0) er[row] = s;
    }
    if (t < 64) {
        diag_l[t] = 0.f;
        float sg = params[0];
        f_reg = invN*(Yp2[t] + a1_l[t]*rp2_s + ar[t]*sg) + a1_l[t]*sg + Wbv[obase + t];
        fv[b*256 + obase + t] = f_reg;
    }
    __syncthreads();

    // GEMM3: Z = E_sl * S ; diag[o] = sum_c2 Z[o][c2]*E[o][c2]
    f32x4 accZ[4][2];
    #pragma unroll
    for (int i = 0; i < 4; ++i) { accZ[i][0] = (f32x4){0,0,0,0}; accZ[i][1] = (f32x4){0,0,0,0}; }
    #pragma unroll
    for (int ks = 0; ks < 8; ++ks) {
        bf16x8 a4[4], b2[2];
        #pragma unroll
        for (int mi = 0; mi < 4; ++mi) {
            int ol = mi*16 + lr;
            a4[mi] = __builtin_bit_cast(bf16x8, *(const u16x8*)&Ebuf[ol*256 + ((ks*32 + lg*8) ^ ((ol&7)<<3))]);
        }
        #pragma unroll
        for (int ni = 0; ni < 2; ++ni)
            b2[ni] = __builtin_bit_cast(bf16x8, *(const u16x8*)(Sb + (size_t)(wv*32+ni*16+lr)*256 + ks*32 + lg*8));
        #pragma unroll
        for (int mi = 0; mi < 4; ++mi)
            #pragma unroll
            for (int ni = 0; ni < 2; ++ni)
                accZ[mi][ni] = MFMA(a4[mi], b2[ni], accZ[mi][ni]);
    }
    #pragma unroll
    for (int mi = 0; mi < 4; ++mi)
        #pragma unroll
        for (int j = 0; j < 4; ++j) {
            int ol = mi*16 + lg*4 + j;
            float s = 0.f;
            #pragma unroll
            for (int ni = 0; ni < 2; ++ni) {
                int c2 = wv*32 + ni*16 + lr;
                s += accZ[mi][ni][j] * bf2f(Ebuf[ol*256 + (c2 ^ ((ol&7)<<3))]);
            }
            s += __shfl_xor(s, 1); s += __shfl_xor(s, 2);
            s += __shfl_xor(s, 4); s += __shfl_xor(s, 8);
            if (lr == 0) atomicAdd(&diag_l[ol], s);
        }
    __syncthreads();

    if (t < 64) {
        int o = obase + t;
        atomicAdd(&stats[o], er[t] + 4096.0f*f_reg);
        atomicAdd(&stats[256 + o], diag_l[t] + 2.0f*f_reg*er[t] + 4096.0f*f_reg*f_reg);
    }
}

// ============ kF: out = (E x + f - mu)*gamma*rsqrt(var+eps) + beta + x  (coalesced stores) ============
__global__ __launch_bounds__(512) void kF(
    const float* __restrict__ x, const unsigned short* __restrict__ Ebf,
    const float* __restrict__ fv, const float* __restrict__ stats,
    const float* __restrict__ gamma, const float* __restrict__ beta,
    float* __restrict__ out)
{
    __shared__ __align__(16) unsigned short Xs[128*256];  // 64 KB, [n][c] swz
    __shared__ float scale_l[256], shift_l[256];
    int b = blockIdx.x >> 5, n0 = (blockIdx.x & 31) * 128;
    int t = threadIdx.x, lane = t & 63, wv = t >> 6, lr = lane & 15, lg = lane >> 4;
    const float inv = 1.0f / 32768.0f;
    if (t < 256) {
        float mu  = stats[t] * inv;
        float var = stats[256 + t] * inv - mu*mu;
        float sc  = gamma[t] * rsqrtf(var + 1e-5f);
        scale_l[t] = sc;
        shift_l[t] = (fv[b*256 + t] - mu) * sc + beta[t];
    }
    {
        int nq = (t & 31) * 4, c0 = (t >> 5) * 4;
        const float* xb = x + (size_t)b*CIN*NN + n0 + nq;
        #pragma unroll
        for (int p = 0; p < 4; ++p) {
            int c = p*64 + c0;
            const float* xp = xb + (size_t)c*NN;
            float4 f0 = *(const float4*)(xp);
            float4 f1 = *(const float4*)(xp + NN);
            float4 f2 = *(const float4*)(xp + 2*NN);
            float4 f3 = *(const float4*)(xp + 3*NN);
            *(ushort4*)&Xs[(nq+0)*256 + (c ^ (((nq+0)&7)<<3))] = pack4(f0.x,f1.x,f2.x,f3.x);
            *(ushort4*)&Xs[(nq+1)*256 + (c ^ (((nq+1)&7)<<3))] = pack4(f0.y,f1.y,f2.y,f3.y);
            *(ushort4*)&Xs[(nq+2)*256 + (c ^ (((nq+2)&7)<<3))] = pack4(f0.z,f1.z,f2.z,f3.z);
            *(ushort4*)&Xs[(nq+3)*256 + (c ^ (((nq+3)&7)<<3))] = pack4(f0.w,f1.w,f2.w,f3.w);
        }
    }
    __syncthreads();

    int wn = wv >> 2, wo = wv & 3;
    int nb = wn*64, ob = wo*64;
    const unsigned short* Eb = Ebf + (size_t)b*65536;
    f32x4 acc[4][4];   // [oi][ni]
    #pragma unroll
    for (int i = 0; i < 4; ++i)
        #pragma unroll
        for (int j = 0; j < 4; ++j) acc[i][j] = (f32x4){0,0,0,0};

    #pragma unroll
    for (int ks = 0; ks < 8; ++ks) {
        bf16x8 xf[4], ef[4];
        #pragma unroll
        for (int ni = 0; ni < 4; ++ni) {
            int n = nb + ni*16 + lr;
            xf[ni] = __builtin_bit_cast(bf16x8, *(const u16x8*)&Xs[(n*256 + ks*32 + lg*8) ^ ((n&7)<<3)]);
        }
        #pragma unroll
        for (int oi = 0; oi < 4; ++oi) {
            int o = ob + oi*16 + lr;
            ef[oi] = __builtin_bit_cast(bf16x8, *(const u16x8*)(Eb + (size_t)o*256 + ks*32 + lg*8));
        }
        #pragma unroll
        for (int oi = 0; oi < 4; ++oi)
            #pragma unroll
            for (int ni = 0; ni < 4; ++ni)
                acc[oi][ni] = MFMA(ef[oi], xf[ni], acc[oi][ni]);
    }

    float* op = out + (size_t)b*CIN*NN + n0;
    #pragma unroll
    for (int oi = 0; oi < 4; ++oi) {
        #pragma unroll
        for (int j = 0; j < 4; ++j) {
            int o = ob + oi*16 + lg*4 + j;
            float sc = scale_l[o], sh = shift_l[o];
            #pragma unroll
            for (int ni = 0; ni < 4; ++ni) {
                int n = nb + ni*16 + lr;
                float val = acc[oi][ni][j]*sc + sh + bf2f(Xs[(n*256 + (o ^ ((n&7)<<3)))]);
                op[(size_t)o*NN + n] = val;
            }
        }
    }
}

extern "C" void kernel_launch(void* const* d_in, const int* in_sizes, int n_in,
                              void* d_out, int out_size, void* d_ws, size_t ws_size,
                              hipStream_t stream)
{
    (void)in_sizes; (void)n_in; (void)out_size; (void)ws_size;
    const float* x     = (const float*)d_in[0];
    const float* gw    = (const float*)d_in[1];
    const float* gb    = (const float*)d_in[2];
    const float* tw    = (const float*)d_in[3];
    const float* tb    = (const float*)d_in[4];
    const float* pw    = (const float*)d_in[5];
    const float* pb    = (const float*)d_in[6];
    const float* Ww    = (const float*)d_in[7];
    const float* Wb    = (const float*)d_in[8];
    const float* gamma = (const float*)d_in[9];
    const float* beta  = (const float*)d_in[10];
    float* out = (float*)d_out;

    char* ws = (char*)d_ws;
    unsigned short* Sp  = (unsigned short*)(ws + 0);          // 16 MB
    float* Rp           = (float*)(ws + 16777216);            // 128 KB
    unsigned short* Sbf = (unsigned short*)(ws + 16908288);   // 1 MB
    float* rv           = (float*)(ws + 17956864);            // 8 KB
    unsigned short* Abf = (unsigned short*)(ws + 17965056);   // 128 KB
    unsigned short* CmT = (unsigned short*)(ws + 18096128);   // 128 KB
    unsigned short* Ebf = (unsigned short*)(ws + 18227200);   // 1 MB
    float* fv           = (float*)(ws + 19275776);            // 8 KB
    float* a1           = (float*)(ws + 19283968);            // 1 KB
    float* c1v          = (float*)(ws + 19284992);            // 1 KB
    float* p2           = (float*)(ws + 19286016);            // 1 KB
    float* params       = (float*)(ws + 19287040);            // 64 B
    float* stats        = (float*)(ws + 19287104);            // 2 KB

    kA<<<130, 512, 0, stream>>>(x, Ww, gw, tw, pw, gb, pb, tb,
                                Sp, Rp, Abf, CmT, a1, c1v, p2, params, stats);
    kR<<<136, 512, 0, stream>>>(Sp, Rp, Sbf, rv);
    kE<<<32,  512, 0, stream>>>(Sbf, rv, Abf, CmT, a1, c1v, p2, params, Wb, Ebf, fv, stats);
    kF<<<256, 512, 0, stream>>>(x, Ebf, fv, stats, gamma, beta, out);
}